// Round 14
// baseline (837.374 us; speedup 1.0000x reference)
//
#include <hip/hip_runtime.h>
#include <hip/hip_bf16.h>

// ---------------------------------------------------------------------------
// PointNet++ critic forward. B=32, N=4096.
// R14: bf16 activations end-to-end (numerically identical to R13: rounding
// moved from MFMA-read to write; RNE is monotone so max/round commute).
// l1p/X3/Y1/Y2 bf16; LDS act buffers bf16 in fragment layout (stride 72/136,
// 16B-aligned b128 frags, 2-way conflicts only). Kills all K-loop f2bf,
// halves act traffic; mlp2 LDS 68->36KB (occupancy 2->4). FPS/bq/fchead as-is.
// ---------------------------------------------------------------------------

typedef __attribute__((ext_vector_type(8))) short short8;
typedef __attribute__((ext_vector_type(4))) float f32x4;
union SV8 { short8 v; ushort u[8]; };

__device__ __forceinline__ ushort f2bf(float x) {
    unsigned u = __float_as_uint(x);
    unsigned r = (u + 0x7fffu + ((u >> 16) & 1u)) >> 16;   // RNE
    return (ushort)r;
}

// ======================= DPP wave64 max-reduce (u64) =======================
template<int CTRL>
__device__ __forceinline__ unsigned long long dpp_mov_u64(unsigned long long x) {
    const int lo = (int)(unsigned)(x & 0xffffffffull);
    const int hi = (int)(unsigned)(x >> 32);
    const int nlo = __builtin_amdgcn_update_dpp(lo, lo, CTRL, 0xf, 0xf, false);
    const int nhi = __builtin_amdgcn_update_dpp(hi, hi, CTRL, 0xf, 0xf, false);
    return ((unsigned long long)(unsigned)nhi << 32) | (unsigned)nlo;
}

__device__ __forceinline__ unsigned long long wave_max_u64(unsigned long long x) {
    unsigned long long y;
    y = dpp_mov_u64<0x111>(x); if (y > x) x = y;   // row_shr:1
    y = dpp_mov_u64<0x112>(x); if (y > x) x = y;   // row_shr:2
    y = dpp_mov_u64<0x114>(x); if (y > x) x = y;   // row_shr:4
    y = dpp_mov_u64<0x118>(x); if (y > x) x = y;   // row_shr:8
    y = dpp_mov_u64<0x142>(x); if (y > x) x = y;   // row_bcast:15
    y = dpp_mov_u64<0x143>(x); if (y > x) x = y;   // row_bcast:31
    return x;
}

// ============================ FPS body (R12) ===============================
template<int N, int S, int NT, bool CHW>
__device__ __forceinline__ void fps_body(const float* __restrict__ xyz,
                                         float* __restrict__ new_xyz,
                                         int b, int t, char* smem) {
    constexpr int P  = N / NT;
    constexpr int NW = NT / 64;
    float4* sxyz = (float4*)smem;
    unsigned long long* rv = (unsigned long long*)(smem + (size_t)N * 16);
    int* sfar = (int*)(smem + (size_t)N * 16 + 2 * NW * 8);
    float px[P], py[P], pz[P], dist[P];
    unsigned idc[P];
    if (CHW) {
        const float* base = xyz + (size_t)b * 3 * N;
        #pragma unroll
        for (int p = 0; p < P; ++p) {
            const int i = p * NT + t;
            px[p] = base[i]; py[p] = base[N + i]; pz[p] = base[2 * N + i];
            sxyz[i] = make_float4(px[p], py[p], pz[p], 0.0f);
        }
    } else {
        const float* base = xyz + (size_t)b * N * 3;
        #pragma unroll
        for (int p = 0; p < P; ++p) {
            const int i = p * NT + t;
            px[p] = base[i*3]; py[p] = base[i*3+1]; pz[p] = base[i*3+2];
            sxyz[i] = make_float4(px[p], py[p], pz[p], 0.0f);
        }
    }
    #pragma unroll
    for (int p = 0; p < P; ++p) { dist[p] = 1e10f; idc[p] = (unsigned)(N - 1 - (p * NT + t)); }
    __syncthreads();
    int far = 0;
    for (int j = 0; j < S; ++j) {
        if (t == 0) sfar[j] = far;           // LDS only — no VMEM in loop
        const float4 cen = sxyz[far];        // broadcast b128
        unsigned long long pk[P];
        #pragma unroll
        for (int p = 0; p < P; ++p) {
            const float dx = px[p] - cen.x, dy = py[p] - cen.y, dz = pz[p] - cen.z;
            // match reference rounding exactly: no FMA contraction
            const float d = __fadd_rn(__fadd_rn(__fmul_rn(dx, dx), __fmul_rn(dy, dy)), __fmul_rn(dz, dz));
            const float nd = fminf(dist[p], d);
            dist[p] = nd;
            pk[p] = ((unsigned long long)__float_as_uint(nd) << 32) | idc[p];
        }
        #pragma unroll
        for (int s = P / 2; s > 0; s >>= 1)
            #pragma unroll
            for (int k = 0; k < s; ++k)
                if (pk[k + s] > pk[k]) pk[k] = pk[k + s];
        unsigned long long best = wave_max_u64(pk[0]);
        if constexpr (NW > 1) {
            const int sl = (j & 1) * NW;     // parity slots: overwrite-safe
            if ((t & 63) == 63) rv[sl + (t >> 6)] = best;
            __syncthreads();
            unsigned long long bb = rv[sl];
            #pragma unroll
            for (int w = 1; w < NW; ++w) { const unsigned long long v = rv[sl + w]; if (v > bb) bb = v; }
            far = N - 1 - (int)(bb & 0xffffffffull);
        } else {
            far = N - 1 - __builtin_amdgcn_readlane((int)(best & 0xffffffffull), 63);
        }
    }
    __syncthreads();
    float* out = new_xyz + (size_t)b * S * 3;
    for (int i = t; i < S; i += NT) {
        const float4 c = sxyz[sfar[i]];
        out[i*3+0] = c.x; out[i*3+1] = c.y; out[i*3+2] = c.z;
    }
}

// ==================== weight bf16 tile pack (h only) =======================
__device__ __forceinline__ void packg(const float* __restrict__ src,
                                      ushort* __restrict__ dh,
                                      int Ktot, int otiles, int cofs, int idx) {
    const int j = idx & 7, lane = (idx >> 3) & 63;
    const int ot = (idx >> 9) % otiles;
    const int ks = idx / (512 * otiles);
    const int m = lane & 15, q = lane >> 4;
    const int o = ot * 16 + m, c = cofs + ks * 32 + q * 8 + j;
    const float v = (c < Ktot) ? src[(size_t)o * Ktot + c] : 0.0f;
    dh[idx] = f2bf(v);
}

// ================= fps1 + weight pack, merged launch =======================
__global__ __launch_bounds__(256)
void fps1_prep_kernel(const float* __restrict__ xyz, float* __restrict__ l1xyz,
                 const float* s1w0, const float* s1b0, float4* Wc1,
                 const float* s1w1, ushort* M1W1h,
                 const float* s1w2, ushort* M1W2h,
                 const float* s3w0, ushort* S3W0h,
                 const float* s3w1, ushort* S3W1h,
                 const float* s3w2, ushort* S3W2h,
                 const float* s2w0, const float* s2b0, float4* Wc0,
                 ushort* W0h,
                 const float* s2w1, ushort* W1h,
                 const float* s2w2, ushort* W2h) {
    __shared__ __align__(16) char smem[4096 * 16 + 64 + 512 * 4];
    if (blockIdx.x < 32) {
        fps_body<4096, 512, 256, true>(xyz, l1xyz, blockIdx.x, threadIdx.x, smem);
        return;
    }
    int i = (blockIdx.x - 32) * 256 + threadIdx.x;
    if (i < 64)     { Wc1[i] = make_float4(s1w0[i*3], s1w0[i*3+1], s1w0[i*3+2], s1b0[i]); return; }  i -= 64;
    if (i < 4096)   { packg(s1w1, M1W1h,  64,  4, 0, i); return; }   i -= 4096;
    if (i < 8192)   { packg(s1w2, M1W2h,  64,  8, 0, i); return; }   i -= 8192;
    if (i < 73728)  { packg(s3w0, S3W0h, 259, 16, 0, i); return; }   i -= 73728;
    if (i < 131072) { packg(s3w1, S3W1h, 256, 32, 0, i); return; }   i -= 131072;
    if (i < 524288) { packg(s3w2, S3W2h, 512, 64, 0, i); return; }   i -= 524288;
    if (i < 16384)  { packg(s2w0, W0h, 131,  8, 3, i); return; }     i -= 16384;
    if (i < 16384)  { packg(s2w1, W1h, 128,  8, 0, i); return; }     i -= 16384;
    if (i < 32768)  { packg(s2w2, W2h, 128, 16, 0, i); return; }     i -= 32768;
    if (i < 128) {
        Wc0[i] = make_float4(s2w0[(size_t)i*131+0], s2w0[(size_t)i*131+1],
                             s2w0[(size_t)i*131+2], s2b0[i]);
    }
}

// ============================ Ball query ===================================
template<int N, int NS, bool CHW, int NT>
__global__ __launch_bounds__(NT)
void bq_kernel(float r2, const float* __restrict__ xyz, const float* __restrict__ cen,
               int* __restrict__ gidx, int S) {
    constexpr int WPB = NT / 64;
    __shared__ __align__(16) float4 sp[N];
    const int t = threadIdx.x, lane = t & 63, w = t >> 6;
    const int cen0 = blockIdx.x * WPB;
    const int b = cen0 / S;                     // WPB divides S -> same batch
    if (CHW) {
        const float* base = xyz + (size_t)b * 3 * N;
        for (int i = t; i < N; i += NT)
            sp[i] = make_float4(base[i], base[N + i], base[2 * N + i], 0.0f);
    } else {
        const float* base = xyz + (size_t)b * N * 3;
        for (int i = t; i < N; i += NT)
            sp[i] = make_float4(base[i*3], base[i*3+1], base[i*3+2], 0.0f);
    }
    __syncthreads();
    const int wid = cen0 + w;
    const float cx = cen[(size_t)wid*3+0], cy = cen[(size_t)wid*3+1], cz = cen[(size_t)wid*3+2];
    int* out = gidx + (size_t)wid * NS;
    int cnt = 0, first = -1;
    for (int b0 = 0; b0 < N; b0 += 64) {
        const float4 p = sp[b0 + lane];
        const float dx = p.x - cx, dy = p.y - cy, dz = p.z - cz;
        const float d = __fadd_rn(__fadd_rn(__fmul_rn(dx, dx), __fmul_rn(dy, dy)), __fmul_rn(dz, dz));
        const bool in = (d <= r2);
        const unsigned long long m = __ballot(in);
        if (first < 0 && m != 0ull) first = b0 + __ffsll((unsigned long long)m) - 1;
        const int pos = cnt + (int)__popcll(m & ((1ull << lane) - 1ull));
        if (in && pos < NS) out[pos] = b0 + lane;
        cnt += (int)__popcll(m);
        if (cnt >= NS) break;
    }
    if (cnt < NS)
        for (int k = cnt + lane; k < NS; k += 64) out[k] = first;
}

// ==================== MLP stage 1 (bf16 acts) + fps2 merged ================
// LDS: g fp32 1KB | hA ushort 64x72 (9216B, later fp32 partials 8192B) |
//      hB ushort 64x72.  fps2 path needs 10304B.
__global__ __launch_bounds__(256)
void mlp1_kernel(const float* __restrict__ xyz, const float* __restrict__ l1xyz,
                 float* __restrict__ l2xyz,
                 const int* __restrict__ gidx, const float4* __restrict__ Wc1,
                 const ushort* __restrict__ W1h, const float* __restrict__ b1,
                 const ushort* __restrict__ W2h, const float* __restrict__ b2,
                 ushort* __restrict__ l1p) {
    __shared__ __align__(16) char smem[20480];
    const int t = threadIdx.x, b = blockIdx.y;
    if (blockIdx.x == 256) {   // fps2
        fps_body<512, 128, 256, false>(l1xyz, l2xyz, b, t, smem);
        return;
    }
    float*  g  = (float*)smem;                        // 64*4 fp32
    ushort* hA = (ushort*)(smem + 1024);              // 64*72 bf16 (h0)
    ushort* hB = (ushort*)(smem + 1024 + 9216);       // 64*72 bf16 (h1)
    float*  red = (float*)(smem + 1024);              // 16*128 fp32 partials (reuse hA)
    const int s0 = blockIdx.x * 2;
    {
        const int n = t >> 2, c = t & 3;
        const int s = s0 + (n >> 5);
        const int gi = gidx[((size_t)b * 512 + s) * 32 + (n & 31)];
        float v = 0.0f;
        if (c < 3) v = xyz[(size_t)b * 3 * 4096 + c * 4096 + gi] - l1xyz[((size_t)b * 512 + s) * 3 + c];
        g[n * 4 + c] = v;
    }
    __syncthreads();
    {   // layer0: 3 -> 64, exact fp32, write bf16
        const int o = t & 63, ng = t >> 6;
        const float4 wc = Wc1[o];
        #pragma unroll
        for (int r = 0; r < 16; ++r) {
            const int n = ng * 16 + r;
            const float z = wc.w + wc.x * g[n*4] + wc.y * g[n*4+1] + wc.z * g[n*4+2];
            hA[n * 72 + o] = f2bf(fmaxf(z, 0.0f));
        }
    }
    const int lane = t & 63, wv = t >> 6;
    const int m = lane & 15, q = lane >> 4;
    const int rowA = wv * 16 + m;
    // layer1: 64 -> 64  [wave-private bands]
    f32x4 acc1[4];
    #pragma unroll
    for (int ot = 0; ot < 4; ++ot)
        #pragma unroll
        for (int r = 0; r < 4; ++r) acc1[ot][r] = 0.0f;
    #pragma unroll
    for (int ks = 0; ks < 2; ++ks) {
        const short8 av = *(const short8*)&hA[rowA * 72 + ks * 32 + q * 8];
        #pragma unroll
        for (int ot = 0; ot < 4; ++ot) {
            const short8 bv = *(const short8*)(W1h + (size_t)((ks * 4 + ot) * 64 + lane) * 8);
            acc1[ot] = __builtin_amdgcn_mfma_f32_16x16x32_bf16(av, bv, acc1[ot], 0, 0, 0);
        }
    }
    #pragma unroll
    for (int ot = 0; ot < 4; ++ot) {
        const float bb = b1[ot * 16 + m];
        #pragma unroll
        for (int r = 0; r < 4; ++r)
            hB[(wv * 16 + q * 4 + r) * 72 + ot * 16 + m] = f2bf(fmaxf(acc1[ot][r] + bb, 0.0f));
    }
    // layer2: 64 -> 128 + per-wave max  [wave-private]
    f32x4 acc2[8];
    #pragma unroll
    for (int ot = 0; ot < 8; ++ot)
        #pragma unroll
        for (int r = 0; r < 4; ++r) acc2[ot][r] = 0.0f;
    #pragma unroll
    for (int ks = 0; ks < 2; ++ks) {
        const short8 av = *(const short8*)&hB[rowA * 72 + ks * 32 + q * 8];
        #pragma unroll
        for (int ot = 0; ot < 8; ++ot) {
            const short8 bv = *(const short8*)(W2h + (size_t)((ks * 8 + ot) * 64 + lane) * 8);
            acc2[ot] = __builtin_amdgcn_mfma_f32_16x16x32_bf16(av, bv, acc2[ot], 0, 0, 0);
        }
    }
    __syncthreads();     // all hA reads done; reuse as fp32 partials
    #pragma unroll
    for (int ot = 0; ot < 8; ++ot) {
        const float bb = b2[ot * 16 + m];
        float mx = 0.0f;
        #pragma unroll
        for (int r = 0; r < 4; ++r) mx = fmaxf(mx, acc2[ot][r] + bb);
        red[(wv * 4 + q) * 128 + ot * 16 + m] = mx;
    }
    __syncthreads();
    {
        const int half = t >> 7, o = t & 127;
        float v = red[(half * 8) * 128 + o];
        #pragma unroll
        for (int rr = 1; rr < 8; ++rr) v = fmaxf(v, red[(half * 8 + rr) * 128 + o]);
        l1p[((size_t)b * 512 + s0 + half) * 128 + o] = f2bf(v);
    }
}

// ============================ MLP stage 2 (bf16 acts) ======================
// LDS: sg 256B | crd fp32 1KB | Abuf ushort 64x136 | Bbuf ushort 64x136
//      (Bbuf reused as fp32 partials 16KB). ~36KB -> 4 blocks/CU.
__global__ __launch_bounds__(256)
void mlp2_kernel(const float* __restrict__ l1xyz, const ushort* __restrict__ l1p,
                 const float* __restrict__ l2xyz, const int* __restrict__ gidx,
                 const ushort* __restrict__ W0h, const float4* __restrict__ Wc0,
                 const ushort* __restrict__ W1h, const float* __restrict__ b1,
                 const ushort* __restrict__ W2h, const float* __restrict__ b2,
                 ushort* __restrict__ X3) {
    __shared__ int sg[64];
    __shared__ __align__(16) float crd[64 * 4];
    __shared__ __align__(16) ushort Abuf[64 * 136];   // x-feats / h2
    __shared__ __align__(16) ushort Bbuf[64 * 136];   // h1 / fp32 partials
    float* Bf = (float*)Bbuf;
    const int t = threadIdx.x, bs = blockIdx.x, b = bs >> 7;
    if (t < 64) sg[t] = gidx[(size_t)bs * 64 + t];
    if (t < 3)  X3[(size_t)bs * 288 + t] = f2bf(l2xyz[(size_t)bs * 3 + t]);   // coords (bf16, gemm1 rounds anyway)
    if (t >= 64 && t < 93) X3[(size_t)bs * 288 + 259 + (t - 64)] = 0;         // zero pad
    __syncthreads();
    for (int i = t; i < 64 * 16; i += 256) {          // feats: 16B chunks of bf16 l1p rows
        const int n = i >> 4, cc = i & 15;
        *(uint4*)&Abuf[n * 136 + cc * 8] =
            *(const uint4*)&l1p[((size_t)b * 512 + sg[n]) * 128 + cc * 8];
    }
    if (t < 192) {
        const int n = t / 3, c = t % 3;
        crd[n * 4 + c] = l1xyz[((size_t)b * 512 + sg[n]) * 3 + c] - l2xyz[(size_t)bs * 3 + c];
    }
    __syncthreads();
    const int lane = t & 63, wv = t >> 6;
    const int m = lane & 15, q = lane >> 4;
    const int rowA = wv * 16 + m;

    // layer 0: feats (K=128) MFMA + coords/bias fp32 epilogue
    f32x4 acc0[8];
    #pragma unroll
    for (int ot = 0; ot < 8; ++ot)
        #pragma unroll
        for (int r = 0; r < 4; ++r) acc0[ot][r] = 0.0f;
    #pragma unroll
    for (int ks = 0; ks < 4; ++ks) {
        const short8 av = *(const short8*)&Abuf[rowA * 136 + ks * 32 + q * 8];
        #pragma unroll
        for (int ot = 0; ot < 8; ++ot) {
            const short8 bv = *(const short8*)(W0h + (size_t)((ks * 8 + ot) * 64 + lane) * 8);
            acc0[ot] = __builtin_amdgcn_mfma_f32_16x16x32_bf16(av, bv, acc0[ot], 0, 0, 0);
        }
    }
    float cr[4][3];
    #pragma unroll
    for (int r = 0; r < 4; ++r) {
        const int n = wv * 16 + q * 4 + r;
        cr[r][0] = crd[n * 4 + 0]; cr[r][1] = crd[n * 4 + 1]; cr[r][2] = crd[n * 4 + 2];
    }
    #pragma unroll
    for (int ot = 0; ot < 8; ++ot) {
        const float4 wc = Wc0[ot * 16 + m];
        #pragma unroll
        for (int r = 0; r < 4; ++r) {
            const float v = acc0[ot][r] + wc.w + wc.x * cr[r][0] + wc.y * cr[r][1] + wc.z * cr[r][2];
            Bbuf[(wv * 16 + q * 4 + r) * 136 + ot * 16 + m] = f2bf(fmaxf(v, 0.0f));
        }
    }
    __syncthreads();

    // layer 1: 128 -> 128
    f32x4 acc1[8];
    #pragma unroll
    for (int ot = 0; ot < 8; ++ot)
        #pragma unroll
        for (int r = 0; r < 4; ++r) acc1[ot][r] = 0.0f;
    #pragma unroll
    for (int ks = 0; ks < 4; ++ks) {
        const short8 av = *(const short8*)&Bbuf[rowA * 136 + ks * 32 + q * 8];
        #pragma unroll
        for (int ot = 0; ot < 8; ++ot) {
            const short8 bv = *(const short8*)(W1h + (size_t)((ks * 8 + ot) * 64 + lane) * 8);
            acc1[ot] = __builtin_amdgcn_mfma_f32_16x16x32_bf16(av, bv, acc1[ot], 0, 0, 0);
        }
    }
    __syncthreads();
    #pragma unroll
    for (int ot = 0; ot < 8; ++ot) {
        const float bb = b1[ot * 16 + m];
        #pragma unroll
        for (int r = 0; r < 4; ++r)
            Abuf[(wv * 16 + q * 4 + r) * 136 + ot * 16 + m] = f2bf(fmaxf(acc1[ot][r] + bb, 0.0f));
    }
    __syncthreads();

    // layer 2: 128 -> 256, relu+max
    f32x4 acc2[16];
    #pragma unroll
    for (int ot = 0; ot < 16; ++ot)
        #pragma unroll
        for (int r = 0; r < 4; ++r) acc2[ot][r] = 0.0f;
    #pragma unroll
    for (int ks = 0; ks < 4; ++ks) {
        const short8 av = *(const short8*)&Abuf[rowA * 136 + ks * 32 + q * 8];
        #pragma unroll
        for (int ot = 0; ot < 16; ++ot) {
            const short8 bv = *(const short8*)(W2h + (size_t)((ks * 16 + ot) * 64 + lane) * 8);
            acc2[ot] = __builtin_amdgcn_mfma_f32_16x16x32_bf16(av, bv, acc2[ot], 0, 0, 0);
        }
    }
    __syncthreads();       // Bbuf h1 reads done; reuse as fp32 partials
    #pragma unroll
    for (int ot = 0; ot < 16; ++ot) {
        const float bb = b2[ot * 16 + m];
        float mx = 0.0f;
        #pragma unroll
        for (int r = 0; r < 4; ++r) mx = fmaxf(mx, acc2[ot][r] + bb);
        Bf[(wv * 4 + q) * 256 + ot * 16 + m] = mx;
    }
    __syncthreads();
    {
        float v = Bf[t];
        #pragma unroll
        for (int rr = 1; rr < 16; ++rr) v = fmaxf(v, Bf[rr * 256 + t]);
        X3[(size_t)bs * 288 + 3 + t] = f2bf(v);
    }
}

// ============== stage-3 GEMM via MFMA, bf16 A/W (no LDS A) =================
template<int KSTEPS, bool MAXOUT>
__global__ __launch_bounds__(256)
void gemm_mfma_kernel(const ushort* __restrict__ A, int AS,
                      const ushort* __restrict__ Wh,
                      const float* __restrict__ bias, void* __restrict__ Cv, int O) {
    __shared__ float part[16][64];
    const int t = threadIdx.x, lane = t & 63, wv = t >> 6;
    const int m = lane & 15, q = lane >> 4;
    const int rowA = blockIdx.x * 64 + wv * 16 + m;
    const int bo = blockIdx.y, OT = O >> 4;
    f32x4 acc[4];
    #pragma unroll
    for (int ot = 0; ot < 4; ++ot)
        #pragma unroll
        for (int r = 0; r < 4; ++r) acc[ot][r] = 0.0f;
    for (int ks = 0; ks < KSTEPS; ++ks) {
        const short8 av = *(const short8*)&A[(size_t)rowA * AS + ks * 32 + q * 8];
        #pragma unroll
        for (int ot = 0; ot < 4; ++ot) {
            const short8 bv = *(const short8*)(Wh + (size_t)((ks * OT + bo * 4 + ot) * 64 + lane) * 8);
            acc[ot] = __builtin_amdgcn_mfma_f32_16x16x32_bf16(av, bv, acc[ot], 0, 0, 0);
        }
    }
    if (!MAXOUT) {
        ushort* C = (ushort*)Cv;
        #pragma unroll
        for (int ot = 0; ot < 4; ++ot) {
            const int col = (bo * 4 + ot) * 16 + m;
            const float bb = bias[col];
            #pragma unroll
            for (int r = 0; r < 4; ++r) {
                const int row = blockIdx.x * 64 + wv * 16 + q * 4 + r;
                C[(size_t)row * O + col] = f2bf(fmaxf(acc[ot][r] + bb, 0.0f));
            }
        }
    } else {
        float* C = (float*)Cv;
        #pragma unroll
        for (int ot = 0; ot < 4; ++ot) {
            const int col = (bo * 4 + ot) * 16 + m;
            const float bb = bias[col];
            float mx = 0.0f;
            #pragma unroll
            for (int r = 0; r < 4; ++r) mx = fmaxf(mx, acc[ot][r] + bb);
            part[wv * 4 + q][ot * 16 + m] = mx;
        }
        __syncthreads();
        if (t < 64) {
            float v = part[0][t];
            #pragma unroll
            for (int rr = 1; rr < 16; ++rr) v = fmaxf(v, part[rr][t]);
            C[(size_t)blockIdx.x * O + bo * 64 + t] = v;
        }
    }
}

// ================= fused FC head (P3 row-max + 3 layers, fp32) =============
__global__ __launch_bounds__(256)
void fchead_kernel(const float* __restrict__ P3,
                   const float* __restrict__ f1w, const float* __restrict__ f1b,
                   const float* __restrict__ f2w, const float* __restrict__ f2b,
                   const float* __restrict__ f3w, const float* __restrict__ f3b,
                   float* __restrict__ out) {
    __shared__ __align__(16) float x[1024];
    __shared__ __align__(16) float h1[512];
    __shared__ __align__(16) float h2[256];
    const int t = threadIdx.x, b = blockIdx.x;
    for (int i = t; i < 1024; i += 256)
        x[i] = fmaxf(P3[(size_t)(2*b)*1024 + i], P3[(size_t)(2*b+1)*1024 + i]);
    __syncthreads();
    #pragma unroll
    for (int oo = 0; oo < 2; ++oo) {       // f1: 1024 -> 512
        const int o = t + oo * 256;
        const float4* wr = (const float4*)(f1w + (size_t)o * 1024);
        float s0 = 0, s1 = 0, s2 = 0, s3 = 0;
        for (int c = 0; c < 256; ++c) {
            const float4 w4 = wr[c];
            const float4 xv = *(const float4*)&x[c * 4];
            s0 += w4.x * xv.x; s1 += w4.y * xv.y; s2 += w4.z * xv.z; s3 += w4.w * xv.w;
        }
        h1[o] = fmaxf(f1b[o] + ((s0 + s1) + (s2 + s3)), 0.0f);
    }
    __syncthreads();
    {                                       // f2: 512 -> 256
        const float4* wr = (const float4*)(f2w + (size_t)t * 512);
        float s0 = 0, s1 = 0, s2 = 0, s3 = 0;
        for (int c = 0; c < 128; ++c) {
            const float4 w4 = wr[c];
            const float4 xv = *(const float4*)&h1[c * 4];
            s0 += w4.x * xv.x; s1 += w4.y * xv.y; s2 += w4.z * xv.z; s3 += w4.w * xv.w;
        }
        h2[t] = fmaxf(f2b[t] + ((s0 + s1) + (s2 + s3)), 0.0f);
    }
    __syncthreads();
    if (t < 6) {                            // f3: 256 -> 6
        const float4* wr = (const float4*)(f3w + (size_t)t * 256);
        float s0 = 0, s1 = 0, s2 = 0, s3 = 0;
        for (int c = 0; c < 64; ++c) {
            const float4 w4 = wr[c];
            const float4 xv = *(const float4*)&h2[c * 4];
            s0 += w4.x * xv.x; s1 += w4.y * xv.y; s2 += w4.z * xv.z; s3 += w4.w * xv.w;
        }
        out[b * 6 + t] = f3b[t] + ((s0 + s1) + (s2 + s3));
    }
}

// ============================ launch =======================================
extern "C" void kernel_launch(void* const* d_in, const int* in_sizes, int n_in,
                              void* d_out, int out_size, void* d_ws, size_t ws_size,
                              hipStream_t stream) {
    const float* xyz  = (const float*)d_in[0];
    const float* s1w0 = (const float*)d_in[1];  const float* s1b0 = (const float*)d_in[2];
    const float* s1w1 = (const float*)d_in[3];  const float* s1b1 = (const float*)d_in[4];
    const float* s1w2 = (const float*)d_in[5];  const float* s1b2 = (const float*)d_in[6];
    const float* s2w0 = (const float*)d_in[7];  const float* s2b0 = (const float*)d_in[8];
    const float* s2w1 = (const float*)d_in[9];  const float* s2b1 = (const float*)d_in[10];
    const float* s2w2 = (const float*)d_in[11]; const float* s2b2 = (const float*)d_in[12];
    const float* s3w0 = (const float*)d_in[13]; const float* s3b0 = (const float*)d_in[14];
    const float* s3w1 = (const float*)d_in[15]; const float* s3b1 = (const float*)d_in[16];
    const float* s3w2 = (const float*)d_in[17]; const float* s3b2 = (const float*)d_in[18];
    const float* f1w  = (const float*)d_in[19]; const float* f1b  = (const float*)d_in[20];
    const float* f2w  = (const float*)d_in[21]; const float* f2b  = (const float*)d_in[22];
    const float* f3w  = (const float*)d_in[23]; const float* f3b  = (const float*)d_in[24];

    char* ws = (char*)d_ws;
    float*  l1_xyz = (float*) (ws + 0);            // 32*512*3 fp32      (196608)
    int*    gidx1  = (int*)   (ws + 196608);       // 32*512*32         (2097152)
    ushort* l1p    = (ushort*)(ws + 2293760);      // 32*512*128 bf16   (4194304)
    float*  l2_xyz = (float*) (ws + 6488064);      // 32*128*3 fp32     (49152)
    int*    gidx2  = (int*)   (ws + 6537216);      // 32*128*64         (1048576)
    ushort* X3p    = (ushort*)(ws + 7585792);      // 4096*288 bf16     (2359296)
    const size_t PK = 9945088;                     // pack region
    float4* Wc1   = (float4*)(ws + PK + 0);
    ushort* M1W1h = (ushort*)(ws + PK + 1024);
    ushort* M1W2h = (ushort*)(ws + PK + 17408);
    ushort* W0h   = (ushort*)(ws + PK + 50176);
    ushort* W1h   = (ushort*)(ws + PK + 115712);
    ushort* W2h   = (ushort*)(ws + PK + 181248);
    float4* Wc0   = (float4*)(ws + PK + 312320);
    ushort* S3W0h = (ushort*)(ws + PK + 314368);
    ushort* S3W1h = (ushort*)(ws + PK + 609280);
    ushort* S3W2h = (ushort*)(ws + PK + 1133568);
    ushort* Y1 = (ushort*)(ws + 12127232);         // 4096*256 bf16 (2097152)
    ushort* Y2 = (ushort*)(ws + 14224384);         // 4096*512 bf16 (4194304)
    float*  P3 = (float*) (ws + 18418688);         // 64*1024 fp32 partial maxima

    // Stage 1 (fps1 on blocks 0..31, weight pack on blocks 32..)
    fps1_prep_kernel<<<3186, 256, 0, stream>>>(xyz, l1_xyz,
        s1w0, s1b0, Wc1, s1w1, M1W1h, s1w2, M1W2h,
        s3w0, S3W0h, s3w1, S3W1h, s3w2, S3W2h,
        s2w0, s2b0, Wc0, W0h, s2w1, W1h, s2w2, W2h);
    bq_kernel<4096, 32, true, 1024><<<1024, 1024, 0, stream>>>(
        (float)(0.2 * 0.2), xyz, l1_xyz, gidx1, 512);
    {
        dim3 g(257, 32);   // x==256 -> fps2 for batch y
        mlp1_kernel<<<g, 256, 0, stream>>>(xyz, l1_xyz, l2_xyz, gidx1,
            Wc1, M1W1h, s1b1, M1W2h, s1b2, l1p);
    }

    // Stage 2
    bq_kernel<512, 64, false, 1024><<<256, 1024, 0, stream>>>(
        (float)(0.4 * 0.4), l1_xyz, l2_xyz, gidx2, 128);
    mlp2_kernel<<<4096, 256, 0, stream>>>(l1_xyz, l1p, l2_xyz, gidx2,
        W0h, Wc0, W1h, s2b1, W2h, s2b2, X3p);

    // Stage 3 (bf16 MFMA GEMMs; gemm3 fuses the 128-row max into P3)
    {
        dim3 g1(64, 4);
        gemm_mfma_kernel<9,  false><<<g1, 256, 0, stream>>>(X3p, 288, S3W0h, s3b0, Y1, 256);
        dim3 g2(64, 8);
        gemm_mfma_kernel<8,  false><<<g2, 256, 0, stream>>>(Y1, 256, S3W1h, s3b1, Y2, 512);
        dim3 g3(64, 16);
        gemm_mfma_kernel<16, true ><<<g3, 256, 0, stream>>>(Y2, 512, S3W2h, s3b2, P3, 1024);
    }

    // Fused FC head (row-max of P3 + 1024->512->256->6)
    fchead_kernel<<<32, 256, 0, stream>>>(P3, f1w, f1b, f2w, f2b, f3w, f3b, (float*)d_out);
    (void)in_sizes; (void)n_in; (void)out_size; (void)ws_size;
}

// Round 15
// 797.515 us; speedup vs baseline: 1.0500x; 1.0500x over previous
//
#include <hip/hip_runtime.h>
#include <hip/hip_bf16.h>

// ---------------------------------------------------------------------------
// PointNet++ critic forward. B=32, N=4096.
// R15: R13 baseline restored (R14's monolithic bf16-act change regressed +53us
// and is reverted). Single isolated change: gemm_mfma A-reuse x2 for gemm2/3
// (8 otiles/block -> each A load+convert feeds 8 MFMAs; gemm1 stays 4 otiles
// to keep >=256 blocks).
// ---------------------------------------------------------------------------

typedef __attribute__((ext_vector_type(8))) short short8;
typedef __attribute__((ext_vector_type(4))) float f32x4;
union SV8 { short8 v; ushort u[8]; };

__device__ __forceinline__ ushort f2bf(float x) {
    unsigned u = __float_as_uint(x);
    unsigned r = (u + 0x7fffu + ((u >> 16) & 1u)) >> 16;   // RNE
    return (ushort)r;
}

// ======================= DPP wave64 max-reduce (u64) =======================
template<int CTRL>
__device__ __forceinline__ unsigned long long dpp_mov_u64(unsigned long long x) {
    const int lo = (int)(unsigned)(x & 0xffffffffull);
    const int hi = (int)(unsigned)(x >> 32);
    const int nlo = __builtin_amdgcn_update_dpp(lo, lo, CTRL, 0xf, 0xf, false);
    const int nhi = __builtin_amdgcn_update_dpp(hi, hi, CTRL, 0xf, 0xf, false);
    return ((unsigned long long)(unsigned)nhi << 32) | (unsigned)nlo;
}

__device__ __forceinline__ unsigned long long wave_max_u64(unsigned long long x) {
    unsigned long long y;
    y = dpp_mov_u64<0x111>(x); if (y > x) x = y;   // row_shr:1
    y = dpp_mov_u64<0x112>(x); if (y > x) x = y;   // row_shr:2
    y = dpp_mov_u64<0x114>(x); if (y > x) x = y;   // row_shr:4
    y = dpp_mov_u64<0x118>(x); if (y > x) x = y;   // row_shr:8
    y = dpp_mov_u64<0x142>(x); if (y > x) x = y;   // row_bcast:15
    y = dpp_mov_u64<0x143>(x); if (y > x) x = y;   // row_bcast:31
    return x;
}

// ============================ FPS body (R12) ===============================
template<int N, int S, int NT, bool CHW>
__device__ __forceinline__ void fps_body(const float* __restrict__ xyz,
                                         float* __restrict__ new_xyz,
                                         int b, int t, char* smem) {
    constexpr int P  = N / NT;
    constexpr int NW = NT / 64;
    float4* sxyz = (float4*)smem;
    unsigned long long* rv = (unsigned long long*)(smem + (size_t)N * 16);
    int* sfar = (int*)(smem + (size_t)N * 16 + 2 * NW * 8);
    float px[P], py[P], pz[P], dist[P];
    unsigned idc[P];
    if (CHW) {
        const float* base = xyz + (size_t)b * 3 * N;
        #pragma unroll
        for (int p = 0; p < P; ++p) {
            const int i = p * NT + t;
            px[p] = base[i]; py[p] = base[N + i]; pz[p] = base[2 * N + i];
            sxyz[i] = make_float4(px[p], py[p], pz[p], 0.0f);
        }
    } else {
        const float* base = xyz + (size_t)b * N * 3;
        #pragma unroll
        for (int p = 0; p < P; ++p) {
            const int i = p * NT + t;
            px[p] = base[i*3]; py[p] = base[i*3+1]; pz[p] = base[i*3+2];
            sxyz[i] = make_float4(px[p], py[p], pz[p], 0.0f);
        }
    }
    #pragma unroll
    for (int p = 0; p < P; ++p) { dist[p] = 1e10f; idc[p] = (unsigned)(N - 1 - (p * NT + t)); }
    __syncthreads();
    int far = 0;
    for (int j = 0; j < S; ++j) {
        if (t == 0) sfar[j] = far;           // LDS only — no VMEM in loop
        const float4 cen = sxyz[far];        // broadcast b128
        unsigned long long pk[P];
        #pragma unroll
        for (int p = 0; p < P; ++p) {
            const float dx = px[p] - cen.x, dy = py[p] - cen.y, dz = pz[p] - cen.z;
            // match reference rounding exactly: no FMA contraction
            const float d = __fadd_rn(__fadd_rn(__fmul_rn(dx, dx), __fmul_rn(dy, dy)), __fmul_rn(dz, dz));
            const float nd = fminf(dist[p], d);
            dist[p] = nd;
            pk[p] = ((unsigned long long)__float_as_uint(nd) << 32) | idc[p];
        }
        #pragma unroll
        for (int s = P / 2; s > 0; s >>= 1)
            #pragma unroll
            for (int k = 0; k < s; ++k)
                if (pk[k + s] > pk[k]) pk[k] = pk[k + s];
        unsigned long long best = wave_max_u64(pk[0]);
        if constexpr (NW > 1) {
            const int sl = (j & 1) * NW;     // parity slots: overwrite-safe
            if ((t & 63) == 63) rv[sl + (t >> 6)] = best;
            __syncthreads();
            unsigned long long bb = rv[sl];
            #pragma unroll
            for (int w = 1; w < NW; ++w) { const unsigned long long v = rv[sl + w]; if (v > bb) bb = v; }
            far = N - 1 - (int)(bb & 0xffffffffull);
        } else {
            far = N - 1 - __builtin_amdgcn_readlane((int)(best & 0xffffffffull), 63);
        }
    }
    __syncthreads();
    float* out = new_xyz + (size_t)b * S * 3;
    for (int i = t; i < S; i += NT) {
        const float4 c = sxyz[sfar[i]];
        out[i*3+0] = c.x; out[i*3+1] = c.y; out[i*3+2] = c.z;
    }
}

// ==================== weight bf16 tile pack (h only) =======================
__device__ __forceinline__ void packg(const float* __restrict__ src,
                                      ushort* __restrict__ dh,
                                      int Ktot, int otiles, int cofs, int idx) {
    const int j = idx & 7, lane = (idx >> 3) & 63;
    const int ot = (idx >> 9) % otiles;
    const int ks = idx / (512 * otiles);
    const int m = lane & 15, q = lane >> 4;
    const int o = ot * 16 + m, c = cofs + ks * 32 + q * 8 + j;
    const float v = (c < Ktot) ? src[(size_t)o * Ktot + c] : 0.0f;
    dh[idx] = f2bf(v);
}

// ================= fps1 + weight pack, merged launch =======================
__global__ __launch_bounds__(256)
void fps1_prep_kernel(const float* __restrict__ xyz, float* __restrict__ l1xyz,
                 const float* s1w0, const float* s1b0, float4* Wc1,
                 const float* s1w1, ushort* M1W1h,
                 const float* s1w2, ushort* M1W2h,
                 const float* s3w0, ushort* S3W0h,
                 const float* s3w1, ushort* S3W1h,
                 const float* s3w2, ushort* S3W2h,
                 const float* s2w0, const float* s2b0, float4* Wc0,
                 ushort* W0h,
                 const float* s2w1, ushort* W1h,
                 const float* s2w2, ushort* W2h) {
    __shared__ __align__(16) char smem[4096 * 16 + 64 + 512 * 4];
    if (blockIdx.x < 32) {
        fps_body<4096, 512, 256, true>(xyz, l1xyz, blockIdx.x, threadIdx.x, smem);
        return;
    }
    int i = (blockIdx.x - 32) * 256 + threadIdx.x;
    if (i < 64)     { Wc1[i] = make_float4(s1w0[i*3], s1w0[i*3+1], s1w0[i*3+2], s1b0[i]); return; }  i -= 64;
    if (i < 4096)   { packg(s1w1, M1W1h,  64,  4, 0, i); return; }   i -= 4096;
    if (i < 8192)   { packg(s1w2, M1W2h,  64,  8, 0, i); return; }   i -= 8192;
    if (i < 73728)  { packg(s3w0, S3W0h, 259, 16, 0, i); return; }   i -= 73728;
    if (i < 131072) { packg(s3w1, S3W1h, 256, 32, 0, i); return; }   i -= 131072;
    if (i < 524288) { packg(s3w2, S3W2h, 512, 64, 0, i); return; }   i -= 524288;
    if (i < 16384)  { packg(s2w0, W0h, 131,  8, 3, i); return; }     i -= 16384;
    if (i < 16384)  { packg(s2w1, W1h, 128,  8, 0, i); return; }     i -= 16384;
    if (i < 32768)  { packg(s2w2, W2h, 128, 16, 0, i); return; }     i -= 32768;
    if (i < 128) {
        Wc0[i] = make_float4(s2w0[(size_t)i*131+0], s2w0[(size_t)i*131+1],
                             s2w0[(size_t)i*131+2], s2b0[i]);
    }
}

// ============================ Ball query ===================================
template<int N, int NS, bool CHW, int NT>
__global__ __launch_bounds__(NT)
void bq_kernel(float r2, const float* __restrict__ xyz, const float* __restrict__ cen,
               int* __restrict__ gidx, int S) {
    constexpr int WPB = NT / 64;
    __shared__ __align__(16) float4 sp[N];
    const int t = threadIdx.x, lane = t & 63, w = t >> 6;
    const int cen0 = blockIdx.x * WPB;
    const int b = cen0 / S;                     // WPB divides S -> same batch
    if (CHW) {
        const float* base = xyz + (size_t)b * 3 * N;
        for (int i = t; i < N; i += NT)
            sp[i] = make_float4(base[i], base[N + i], base[2 * N + i], 0.0f);
    } else {
        const float* base = xyz + (size_t)b * N * 3;
        for (int i = t; i < N; i += NT)
            sp[i] = make_float4(base[i*3], base[i*3+1], base[i*3+2], 0.0f);
    }
    __syncthreads();
    const int wid = cen0 + w;
    const float cx = cen[(size_t)wid*3+0], cy = cen[(size_t)wid*3+1], cz = cen[(size_t)wid*3+2];
    int* out = gidx + (size_t)wid * NS;
    int cnt = 0, first = -1;
    for (int b0 = 0; b0 < N; b0 += 64) {
        const float4 p = sp[b0 + lane];
        const float dx = p.x - cx, dy = p.y - cy, dz = p.z - cz;
        const float d = __fadd_rn(__fadd_rn(__fmul_rn(dx, dx), __fmul_rn(dy, dy)), __fmul_rn(dz, dz));
        const bool in = (d <= r2);
        const unsigned long long m = __ballot(in);
        if (first < 0 && m != 0ull) first = b0 + __ffsll((unsigned long long)m) - 1;
        const int pos = cnt + (int)__popcll(m & ((1ull << lane) - 1ull));
        if (in && pos < NS) out[pos] = b0 + lane;
        cnt += (int)__popcll(m);
        if (cnt >= NS) break;
    }
    if (cnt < NS)
        for (int k = cnt + lane; k < NS; k += 64) out[k] = first;
}

// ==================== MLP stage 1 (MFMA bf16) + fps2 merged ================
__global__ __launch_bounds__(256)
void mlp1_kernel(const float* __restrict__ xyz, const float* __restrict__ l1xyz,
                 float* __restrict__ l2xyz,
                 const int* __restrict__ gidx, const float4* __restrict__ Wc1,
                 const ushort* __restrict__ W1h, const float* __restrict__ b1,
                 const ushort* __restrict__ W2h, const float* __restrict__ b2,
                 float* __restrict__ l1p) {
    __shared__ __align__(16) char smem[64 * 68 * 4 * 2];   // 34816 B
    float* bufA = (float*)smem;
    float* bufB = (float*)(smem + 64 * 68 * 4);
    const int t = threadIdx.x, b = blockIdx.y;
    if (blockIdx.x == 256) {   // fps2
        fps_body<512, 128, 256, false>(l1xyz, l2xyz, b, t, smem);
        return;
    }
    const int s0 = blockIdx.x * 2;
    {
        const int n = t >> 2, c = t & 3;
        const int s = s0 + (n >> 5);
        const int gi = gidx[((size_t)b * 512 + s) * 32 + (n & 31)];
        float v = 0.0f;
        if (c < 3) v = xyz[(size_t)b * 3 * 4096 + c * 4096 + gi] - l1xyz[((size_t)b * 512 + s) * 3 + c];
        bufB[n * 4 + c] = v;
    }
    __syncthreads();
    {   // layer0: 3 -> 64, exact fp32
        const int o = t & 63, ng = t >> 6;
        const float4 wc = Wc1[o];
        #pragma unroll
        for (int r = 0; r < 16; ++r) {
            const int n = ng * 16 + r;
            const float z = wc.w + wc.x * bufB[n*4] + wc.y * bufB[n*4+1] + wc.z * bufB[n*4+2];
            bufA[n * 68 + o] = fmaxf(z, 0.0f);
        }
    }
    const int lane = t & 63, wv = t >> 6;
    const int m = lane & 15, q = lane >> 4;
    const int rowA = wv * 16 + m;
    // layer1: 64 -> 64
    f32x4 acc1[4];
    #pragma unroll
    for (int ot = 0; ot < 4; ++ot)
        #pragma unroll
        for (int r = 0; r < 4; ++r) acc1[ot][r] = 0.0f;
    #pragma unroll
    for (int ks = 0; ks < 2; ++ks) {
        float xv[8];
        *(float4*)&xv[0] = *(const float4*)&bufA[rowA * 68 + ks * 32 + q * 8];
        *(float4*)&xv[4] = *(const float4*)&bufA[rowA * 68 + ks * 32 + q * 8 + 4];
        SV8 ah;
        #pragma unroll
        for (int j = 0; j < 8; ++j) ah.u[j] = f2bf(xv[j]);
        #pragma unroll
        for (int ot = 0; ot < 4; ++ot) {
            SV8 bh;
            bh.v = *(const short8*)(W1h + (size_t)((ks * 4 + ot) * 64 + lane) * 8);
            acc1[ot] = __builtin_amdgcn_mfma_f32_16x16x32_bf16(ah.v, bh.v, acc1[ot], 0, 0, 0);
        }
    }
    #pragma unroll
    for (int ot = 0; ot < 4; ++ot) {
        const float bb = b1[ot * 16 + m];
        #pragma unroll
        for (int r = 0; r < 4; ++r)
            bufB[(wv * 16 + q * 4 + r) * 68 + ot * 16 + m] = fmaxf(acc1[ot][r] + bb, 0.0f);
    }
    // layer2: 64 -> 128 + per-wave max
    f32x4 acc2[8];
    #pragma unroll
    for (int ot = 0; ot < 8; ++ot)
        #pragma unroll
        for (int r = 0; r < 4; ++r) acc2[ot][r] = 0.0f;
    #pragma unroll
    for (int ks = 0; ks < 2; ++ks) {
        float xv[8];
        *(float4*)&xv[0] = *(const float4*)&bufB[rowA * 68 + ks * 32 + q * 8];
        *(float4*)&xv[4] = *(const float4*)&bufB[rowA * 68 + ks * 32 + q * 8 + 4];
        SV8 ah;
        #pragma unroll
        for (int j = 0; j < 8; ++j) ah.u[j] = f2bf(xv[j]);
        #pragma unroll
        for (int ot = 0; ot < 8; ++ot) {
            SV8 bh;
            bh.v = *(const short8*)(W2h + (size_t)((ks * 8 + ot) * 64 + lane) * 8);
            acc2[ot] = __builtin_amdgcn_mfma_f32_16x16x32_bf16(ah.v, bh.v, acc2[ot], 0, 0, 0);
        }
    }
    __syncthreads();
    #pragma unroll
    for (int ot = 0; ot < 8; ++ot) {
        const float bb = b2[ot * 16 + m];
        float mx = 0.0f;
        #pragma unroll
        for (int r = 0; r < 4; ++r) mx = fmaxf(mx, acc2[ot][r] + bb);
        bufA[(wv * 4 + q) * 128 + ot * 16 + m] = mx;
    }
    __syncthreads();
    {
        const int half = t >> 7, o = t & 127;
        float v = bufA[(half * 8) * 128 + o];
        #pragma unroll
        for (int rr = 1; rr < 8; ++rr) v = fmaxf(v, bufA[(half * 8 + rr) * 128 + o]);
        l1p[((size_t)b * 512 + s0 + half) * 128 + o] = v;
    }
}

// ============================ MLP stage 2 (MFMA bf16) ======================
__global__ __launch_bounds__(256)
void mlp2_kernel(const float* __restrict__ l1xyz, const float* __restrict__ l1p,
                 const float* __restrict__ l2xyz, const int* __restrict__ gidx,
                 const ushort* __restrict__ W0h, const float4* __restrict__ Wc0,
                 const ushort* __restrict__ W1h, const float* __restrict__ b1,
                 const ushort* __restrict__ W2h, const float* __restrict__ b2,
                 float* __restrict__ X3) {
    __shared__ __align__(16) float Abuf[64 * 132];   // x / h2
    __shared__ __align__(16) float Bbuf[64 * 132];   // h1 / max-partials
    __shared__ int sg[64];
    const int t = threadIdx.x, bs = blockIdx.x, b = bs >> 7;
    if (t < 64) sg[t] = gidx[(size_t)bs * 64 + t];
    if (t < 3)  X3[(size_t)bs * 288 + t] = l2xyz[(size_t)bs * 3 + t];     // raw coords
    if (t >= 64 && t < 93) X3[(size_t)bs * 288 + 259 + (t - 64)] = 0.0f;  // zero pad
    __syncthreads();
    for (int i = t; i < 64 * 32; i += 256) {
        const int n = i >> 5, cc = i & 31;
        *(float4*)&Abuf[n * 132 + cc * 4] =
            *(const float4*)&l1p[((size_t)b * 512 + sg[n]) * 128 + cc * 4];
    }
    if (t < 192) {
        const int n = t / 3, c = t % 3;
        Abuf[n * 132 + 128 + c] =
            l1xyz[((size_t)b * 512 + sg[n]) * 3 + c] - l2xyz[(size_t)bs * 3 + c];
    }
    __syncthreads();
    const int lane = t & 63, wv = t >> 6;
    const int m = lane & 15, q = lane >> 4;
    const int rowA = wv * 16 + m;

    // layer 0: feats (K=128) MFMA + coords/bias epilogue
    f32x4 acc0[8];
    #pragma unroll
    for (int ot = 0; ot < 8; ++ot)
        #pragma unroll
        for (int r = 0; r < 4; ++r) acc0[ot][r] = 0.0f;
    #pragma unroll
    for (int ks = 0; ks < 4; ++ks) {
        float xv[8];
        *(float4*)&xv[0] = *(const float4*)&Abuf[rowA * 132 + ks * 32 + q * 8];
        *(float4*)&xv[4] = *(const float4*)&Abuf[rowA * 132 + ks * 32 + q * 8 + 4];
        SV8 ah;
        #pragma unroll
        for (int j = 0; j < 8; ++j) ah.u[j] = f2bf(xv[j]);
        #pragma unroll
        for (int ot = 0; ot < 8; ++ot) {
            SV8 bh;
            bh.v = *(const short8*)(W0h + (size_t)((ks * 8 + ot) * 64 + lane) * 8);
            acc0[ot] = __builtin_amdgcn_mfma_f32_16x16x32_bf16(ah.v, bh.v, acc0[ot], 0, 0, 0);
        }
    }
    float crd[4][3];
    #pragma unroll
    for (int r = 0; r < 4; ++r) {
        const int n = wv * 16 + q * 4 + r;
        crd[r][0] = Abuf[n * 132 + 128];
        crd[r][1] = Abuf[n * 132 + 129];
        crd[r][2] = Abuf[n * 132 + 130];
    }
    #pragma unroll
    for (int ot = 0; ot < 8; ++ot) {
        const float4 wc = Wc0[ot * 16 + m];
        #pragma unroll
        for (int r = 0; r < 4; ++r) {
            const float v = acc0[ot][r] + wc.w + wc.x * crd[r][0] + wc.y * crd[r][1] + wc.z * crd[r][2];
            Bbuf[(wv * 16 + q * 4 + r) * 132 + ot * 16 + m] = fmaxf(v, 0.0f);
        }
    }
    __syncthreads();

    // layer 1: 128 -> 128
    f32x4 acc1[8];
    #pragma unroll
    for (int ot = 0; ot < 8; ++ot)
        #pragma unroll
        for (int r = 0; r < 4; ++r) acc1[ot][r] = 0.0f;
    #pragma unroll
    for (int ks = 0; ks < 4; ++ks) {
        float xv[8];
        *(float4*)&xv[0] = *(const float4*)&Bbuf[rowA * 132 + ks * 32 + q * 8];
        *(float4*)&xv[4] = *(const float4*)&Bbuf[rowA * 132 + ks * 32 + q * 8 + 4];
        SV8 ah;
        #pragma unroll
        for (int j = 0; j < 8; ++j) ah.u[j] = f2bf(xv[j]);
        #pragma unroll
        for (int ot = 0; ot < 8; ++ot) {
            SV8 bh;
            bh.v = *(const short8*)(W1h + (size_t)((ks * 8 + ot) * 64 + lane) * 8);
            acc1[ot] = __builtin_amdgcn_mfma_f32_16x16x32_bf16(ah.v, bh.v, acc1[ot], 0, 0, 0);
        }
    }
    __syncthreads();
    #pragma unroll
    for (int ot = 0; ot < 8; ++ot) {
        const float bb = b1[ot * 16 + m];
        #pragma unroll
        for (int r = 0; r < 4; ++r)
            Abuf[(wv * 16 + q * 4 + r) * 132 + ot * 16 + m] = fmaxf(acc1[ot][r] + bb, 0.0f);
    }
    __syncthreads();

    // layer 2: 128 -> 256, relu+max
    f32x4 acc2[16];
    #pragma unroll
    for (int ot = 0; ot < 16; ++ot)
        #pragma unroll
        for (int r = 0; r < 4; ++r) acc2[ot][r] = 0.0f;
    #pragma unroll
    for (int ks = 0; ks < 4; ++ks) {
        float xv[8];
        *(float4*)&xv[0] = *(const float4*)&Abuf[rowA * 132 + ks * 32 + q * 8];
        *(float4*)&xv[4] = *(const float4*)&Abuf[rowA * 132 + ks * 32 + q * 8 + 4];
        SV8 ah;
        #pragma unroll
        for (int j = 0; j < 8; ++j) ah.u[j] = f2bf(xv[j]);
        #pragma unroll
        for (int ot = 0; ot < 16; ++ot) {
            SV8 bh;
            bh.v = *(const short8*)(W2h + (size_t)((ks * 16 + ot) * 64 + lane) * 8);
            acc2[ot] = __builtin_amdgcn_mfma_f32_16x16x32_bf16(ah.v, bh.v, acc2[ot], 0, 0, 0);
        }
    }
    __syncthreads();
    #pragma unroll
    for (int ot = 0; ot < 16; ++ot) {
        const float bb = b2[ot * 16 + m];
        float mx = 0.0f;
        #pragma unroll
        for (int r = 0; r < 4; ++r) mx = fmaxf(mx, acc2[ot][r] + bb);
        Bbuf[(wv * 4 + q) * 256 + ot * 16 + m] = mx;
    }
    __syncthreads();
    {
        float v = Bbuf[t];
        #pragma unroll
        for (int rr = 1; rr < 16; ++rr) v = fmaxf(v, Bbuf[rr * 256 + t]);
        X3[(size_t)bs * 288 + 3 + t] = v;
    }
}

// ====== stage-3 GEMM via MFMA bf16 (no LDS A), OTILES-parametrized =========
template<int KSTEPS, int OTILES, bool MAXOUT>
__global__ __launch_bounds__(256)
void gemm_mfma_kernel(const float* __restrict__ A, int AS,
                      const ushort* __restrict__ Wh,
                      const float* __restrict__ bias, float* __restrict__ C, int O) {
    __shared__ float part[16][OTILES * 16];
    const int t = threadIdx.x, lane = t & 63, wv = t >> 6;
    const int m = lane & 15, q = lane >> 4;
    const int rowA = blockIdx.x * 64 + wv * 16 + m;
    const int bo = blockIdx.y, OT = O >> 4;
    f32x4 acc[OTILES];
    #pragma unroll
    for (int ot = 0; ot < OTILES; ++ot)
        #pragma unroll
        for (int r = 0; r < 4; ++r) acc[ot][r] = 0.0f;
    for (int ks = 0; ks < KSTEPS; ++ks) {
        float xv[8];
        *(float4*)&xv[0] = *(const float4*)&A[(size_t)rowA * AS + ks * 32 + q * 8];
        *(float4*)&xv[4] = *(const float4*)&A[(size_t)rowA * AS + ks * 32 + q * 8 + 4];
        SV8 ah;
        #pragma unroll
        for (int j = 0; j < 8; ++j) ah.u[j] = f2bf(xv[j]);
        #pragma unroll
        for (int ot = 0; ot < OTILES; ++ot) {
            const size_t wb = (size_t)((ks * OT + bo * OTILES + ot) * 64 + lane) * 8;
            SV8 bh;
            bh.v = *(const short8*)(Wh + wb);
            acc[ot] = __builtin_amdgcn_mfma_f32_16x16x32_bf16(ah.v, bh.v, acc[ot], 0, 0, 0);
        }
    }
    if (!MAXOUT) {
        #pragma unroll
        for (int ot = 0; ot < OTILES; ++ot) {
            const int col = (bo * OTILES + ot) * 16 + m;
            const float bb = bias[col];
            #pragma unroll
            for (int r = 0; r < 4; ++r) {
                const int row = blockIdx.x * 64 + wv * 16 + q * 4 + r;
                C[(size_t)row * O + col] = fmaxf(acc[ot][r] + bb, 0.0f);
            }
        }
    } else {
        #pragma unroll
        for (int ot = 0; ot < OTILES; ++ot) {
            const int col = (bo * OTILES + ot) * 16 + m;
            const float bb = bias[col];
            float mx = 0.0f;
            #pragma unroll
            for (int r = 0; r < 4; ++r) mx = fmaxf(mx, acc[ot][r] + bb);
            part[wv * 4 + q][ot * 16 + m] = mx;
        }
        __syncthreads();
        for (int o = t; o < OTILES * 16; o += 256) {
            float v = part[0][o];
            #pragma unroll
            for (int rr = 1; rr < 16; ++rr) v = fmaxf(v, part[rr][o]);
            C[(size_t)blockIdx.x * O + bo * OTILES * 16 + o] = v;
        }
    }
}

// ================= fused FC head (P3 row-max + 3 layers, fp32) =============
__global__ __launch_bounds__(256)
void fchead_kernel(const float* __restrict__ P3,
                   const float* __restrict__ f1w, const float* __restrict__ f1b,
                   const float* __restrict__ f2w, const float* __restrict__ f2b,
                   const float* __restrict__ f3w, const float* __restrict__ f3b,
                   float* __restrict__ out) {
    __shared__ __align__(16) float x[1024];
    __shared__ __align__(16) float h1[512];
    __shared__ __align__(16) float h2[256];
    const int t = threadIdx.x, b = blockIdx.x;
    for (int i = t; i < 1024; i += 256)
        x[i] = fmaxf(P3[(size_t)(2*b)*1024 + i], P3[(size_t)(2*b+1)*1024 + i]);
    __syncthreads();
    #pragma unroll
    for (int oo = 0; oo < 2; ++oo) {       // f1: 1024 -> 512
        const int o = t + oo * 256;
        const float4* wr = (const float4*)(f1w + (size_t)o * 1024);
        float s0 = 0, s1 = 0, s2 = 0, s3 = 0;
        for (int c = 0; c < 256; ++c) {
            const float4 w4 = wr[c];
            const float4 xv = *(const float4*)&x[c * 4];
            s0 += w4.x * xv.x; s1 += w4.y * xv.y; s2 += w4.z * xv.z; s3 += w4.w * xv.w;
        }
        h1[o] = fmaxf(f1b[o] + ((s0 + s1) + (s2 + s3)), 0.0f);
    }
    __syncthreads();
    {                                       // f2: 512 -> 256
        const float4* wr = (const float4*)(f2w + (size_t)t * 512);
        float s0 = 0, s1 = 0, s2 = 0, s3 = 0;
        for (int c = 0; c < 128; ++c) {
            const float4 w4 = wr[c];
            const float4 xv = *(const float4*)&h1[c * 4];
            s0 += w4.x * xv.x; s1 += w4.y * xv.y; s2 += w4.z * xv.z; s3 += w4.w * xv.w;
        }
        h2[t] = fmaxf(f2b[t] + ((s0 + s1) + (s2 + s3)), 0.0f);
    }
    __syncthreads();
    if (t < 6) {                            // f3: 256 -> 6
        const float4* wr = (const float4*)(f3w + (size_t)t * 256);
        float s0 = 0, s1 = 0, s2 = 0, s3 = 0;
        for (int c = 0; c < 64; ++c) {
            const float4 w4 = wr[c];
            const float4 xv = *(const float4*)&h2[c * 4];
            s0 += w4.x * xv.x; s1 += w4.y * xv.y; s2 += w4.z * xv.z; s3 += w4.w * xv.w;
        }
        out[b * 6 + t] = f3b[t] + ((s0 + s1) + (s2 + s3));
    }
}

// ============================ launch =======================================
extern "C" void kernel_launch(void* const* d_in, const int* in_sizes, int n_in,
                              void* d_out, int out_size, void* d_ws, size_t ws_size,
                              hipStream_t stream) {
    const float* xyz  = (const float*)d_in[0];
    const float* s1w0 = (const float*)d_in[1];  const float* s1b0 = (const float*)d_in[2];
    const float* s1w1 = (const float*)d_in[3];  const float* s1b1 = (const float*)d_in[4];
    const float* s1w2 = (const float*)d_in[5];  const float* s1b2 = (const float*)d_in[6];
    const float* s2w0 = (const float*)d_in[7];  const float* s2b0 = (const float*)d_in[8];
    const float* s2w1 = (const float*)d_in[9];  const float* s2b1 = (const float*)d_in[10];
    const float* s2w2 = (const float*)d_in[11]; const float* s2b2 = (const float*)d_in[12];
    const float* s3w0 = (const float*)d_in[13]; const float* s3b0 = (const float*)d_in[14];
    const float* s3w1 = (const float*)d_in[15]; const float* s3b1 = (const float*)d_in[16];
    const float* s3w2 = (const float*)d_in[17]; const float* s3b2 = (const float*)d_in[18];
    const float* f1w  = (const float*)d_in[19]; const float* f1b  = (const float*)d_in[20];
    const float* f2w  = (const float*)d_in[21]; const float* f2b  = (const float*)d_in[22];
    const float* f3w  = (const float*)d_in[23]; const float* f3b  = (const float*)d_in[24];

    char* ws = (char*)d_ws;
    float* l1_xyz = (float*)(ws + 0);              // 32*512*3
    int*   gidx1  = (int*)  (ws + 196608);         // 32*512*32
    float* l1p    = (float*)(ws + 2293760);        // 32*512*128
    float* l2_xyz = (float*)(ws + 10682368);       // 32*128*3
    int*   gidx2  = (int*)  (ws + 10731520);       // 32*128*64
    float* X3p    = (float*)(ws + 11780096);       // 4096*288 (zero-padded)
    const size_t PK = 16498688;                    // pack region (h-only)
    float4* Wc1   = (float4*)(ws + PK + 0);
    ushort* M1W1h = (ushort*)(ws + PK + 1024);
    ushort* M1W2h = (ushort*)(ws + PK + 17408);
    ushort* W0h   = (ushort*)(ws + PK + 50176);
    ushort* W1h   = (ushort*)(ws + PK + 115712);
    ushort* W2h   = (ushort*)(ws + PK + 181248);
    float4* Wc0   = (float4*)(ws + PK + 312320);
    ushort* S3W0h = (ushort*)(ws + PK + 314368);
    ushort* S3W1h = (ushort*)(ws + PK + 609280);
    ushort* S3W2h = (ushort*)(ws + PK + 1133568);
    float* Y1   = (float*)(ws + 19729408);         // 4096*256
    float* Y2   = (float*)(ws + 23923712);         // 4096*512
    float* P3   = (float*)(ws + 32312320);         // 64*1024 fp32 partial maxima

    // Stage 1 (fps1 on blocks 0..31, weight pack on blocks 32..)
    fps1_prep_kernel<<<3186, 256, 0, stream>>>(xyz, l1_xyz,
        s1w0, s1b0, Wc1, s1w1, M1W1h, s1w2, M1W2h,
        s3w0, S3W0h, s3w1, S3W1h, s3w2, S3W2h,
        s2w0, s2b0, Wc0, W0h, s2w1, W1h, s2w2, W2h);
    bq_kernel<4096, 32, true, 1024><<<1024, 1024, 0, stream>>>(
        (float)(0.2 * 0.2), xyz, l1_xyz, gidx1, 512);
    {
        dim3 g(257, 32);   // x==256 -> fps2 for batch y
        mlp1_kernel<<<g, 256, 0, stream>>>(xyz, l1_xyz, l2_xyz, gidx1,
            Wc1, M1W1h, s1b1, M1W2h, s1b2, l1p);
    }

    // Stage 2
    bq_kernel<512, 64, false, 1024><<<256, 1024, 0, stream>>>(
        (float)(0.4 * 0.4), l1_xyz, l2_xyz, gidx2, 128);
    mlp2_kernel<<<4096, 256, 0, stream>>>(l1_xyz, l1p, l2_xyz, gidx2,
        W0h, Wc0, W1h, s2b1, W2h, s2b2, X3p);

    // Stage 3 (bf16 MFMA GEMMs; gemm2/3 use 8 otiles for A-reuse)
    {
        dim3 g1(64, 4);
        gemm_mfma_kernel<9,  4, false><<<g1, 256, 0, stream>>>(X3p, 288, S3W0h, s3b0, Y1, 256);
        dim3 g2(64, 4);
        gemm_mfma_kernel<8,  8, false><<<g2, 256, 0, stream>>>(Y1, 256, S3W1h, s3b1, Y2, 512);
        dim3 g3(64, 8);
        gemm_mfma_kernel<16, 8, true ><<<g3, 256, 0, stream>>>(Y2, 512, S3W2h, s3b2, P3, 1024);
    }

    // Fused FC head (row-max of P3 + 1024->512->256->6)
    fchead_kernel<<<32, 256, 0, stream>>>(P3, f1w, f1b, f2w, f2b, f3w, f3b, (float*)d_out);
    (void)in_sizes; (void)n_in; (void)out_size; (void)ws_size;
}

// Round 16
// 780.402 us; speedup vs baseline: 1.0730x; 1.0219x over previous
//
#include <hip/hip_runtime.h>
#include <hip/hip_bf16.h>

// ---------------------------------------------------------------------------
// PointNet++ critic forward. B=32, N=4096.
// R16 = R13 exactly (best known, 783.6us). R15's gemm A-reuse reverted
// (OTILES=4 everywhere; 8-otile variant starved gemm2's grid and doubled
// gemm3's per-ks weight-latency chain: +14us). R14's bf16-act reverted
// earlier (+53us). fps = R12 form (serial-latency floor, 4 attack vectors
// measured negative: R9 TLP / R10 tree / R11 mailbox / R12 store-deferral).
// ---------------------------------------------------------------------------

typedef __attribute__((ext_vector_type(8))) short short8;
typedef __attribute__((ext_vector_type(4))) float f32x4;
union SV8 { short8 v; ushort u[8]; };

__device__ __forceinline__ ushort f2bf(float x) {
    unsigned u = __float_as_uint(x);
    unsigned r = (u + 0x7fffu + ((u >> 16) & 1u)) >> 16;   // RNE
    return (ushort)r;
}

// ======================= DPP wave64 max-reduce (u64) =======================
template<int CTRL>
__device__ __forceinline__ unsigned long long dpp_mov_u64(unsigned long long x) {
    const int lo = (int)(unsigned)(x & 0xffffffffull);
    const int hi = (int)(unsigned)(x >> 32);
    const int nlo = __builtin_amdgcn_update_dpp(lo, lo, CTRL, 0xf, 0xf, false);
    const int nhi = __builtin_amdgcn_update_dpp(hi, hi, CTRL, 0xf, 0xf, false);
    return ((unsigned long long)(unsigned)nhi << 32) | (unsigned)nlo;
}

__device__ __forceinline__ unsigned long long wave_max_u64(unsigned long long x) {
    unsigned long long y;
    y = dpp_mov_u64<0x111>(x); if (y > x) x = y;   // row_shr:1
    y = dpp_mov_u64<0x112>(x); if (y > x) x = y;   // row_shr:2
    y = dpp_mov_u64<0x114>(x); if (y > x) x = y;   // row_shr:4
    y = dpp_mov_u64<0x118>(x); if (y > x) x = y;   // row_shr:8
    y = dpp_mov_u64<0x142>(x); if (y > x) x = y;   // row_bcast:15
    y = dpp_mov_u64<0x143>(x); if (y > x) x = y;   // row_bcast:31
    return x;
}

// ============================ FPS body (R12) ===============================
template<int N, int S, int NT, bool CHW>
__device__ __forceinline__ void fps_body(const float* __restrict__ xyz,
                                         float* __restrict__ new_xyz,
                                         int b, int t, char* smem) {
    constexpr int P  = N / NT;
    constexpr int NW = NT / 64;
    float4* sxyz = (float4*)smem;
    unsigned long long* rv = (unsigned long long*)(smem + (size_t)N * 16);
    int* sfar = (int*)(smem + (size_t)N * 16 + 2 * NW * 8);
    float px[P], py[P], pz[P], dist[P];
    unsigned idc[P];
    if (CHW) {
        const float* base = xyz + (size_t)b * 3 * N;
        #pragma unroll
        for (int p = 0; p < P; ++p) {
            const int i = p * NT + t;
            px[p] = base[i]; py[p] = base[N + i]; pz[p] = base[2 * N + i];
            sxyz[i] = make_float4(px[p], py[p], pz[p], 0.0f);
        }
    } else {
        const float* base = xyz + (size_t)b * N * 3;
        #pragma unroll
        for (int p = 0; p < P; ++p) {
            const int i = p * NT + t;
            px[p] = base[i*3]; py[p] = base[i*3+1]; pz[p] = base[i*3+2];
            sxyz[i] = make_float4(px[p], py[p], pz[p], 0.0f);
        }
    }
    #pragma unroll
    for (int p = 0; p < P; ++p) { dist[p] = 1e10f; idc[p] = (unsigned)(N - 1 - (p * NT + t)); }
    __syncthreads();
    int far = 0;
    for (int j = 0; j < S; ++j) {
        if (t == 0) sfar[j] = far;           // LDS only — no VMEM in loop
        const float4 cen = sxyz[far];        // broadcast b128
        unsigned long long pk[P];
        #pragma unroll
        for (int p = 0; p < P; ++p) {
            const float dx = px[p] - cen.x, dy = py[p] - cen.y, dz = pz[p] - cen.z;
            // match reference rounding exactly: no FMA contraction
            const float d = __fadd_rn(__fadd_rn(__fmul_rn(dx, dx), __fmul_rn(dy, dy)), __fmul_rn(dz, dz));
            const float nd = fminf(dist[p], d);
            dist[p] = nd;
            pk[p] = ((unsigned long long)__float_as_uint(nd) << 32) | idc[p];
        }
        #pragma unroll
        for (int s = P / 2; s > 0; s >>= 1)
            #pragma unroll
            for (int k = 0; k < s; ++k)
                if (pk[k + s] > pk[k]) pk[k] = pk[k + s];
        unsigned long long best = wave_max_u64(pk[0]);
        if constexpr (NW > 1) {
            const int sl = (j & 1) * NW;     // parity slots: overwrite-safe
            if ((t & 63) == 63) rv[sl + (t >> 6)] = best;
            __syncthreads();
            unsigned long long bb = rv[sl];
            #pragma unroll
            for (int w = 1; w < NW; ++w) { const unsigned long long v = rv[sl + w]; if (v > bb) bb = v; }
            far = N - 1 - (int)(bb & 0xffffffffull);
        } else {
            far = N - 1 - __builtin_amdgcn_readlane((int)(best & 0xffffffffull), 63);
        }
    }
    __syncthreads();
    float* out = new_xyz + (size_t)b * S * 3;
    for (int i = t; i < S; i += NT) {
        const float4 c = sxyz[sfar[i]];
        out[i*3+0] = c.x; out[i*3+1] = c.y; out[i*3+2] = c.z;
    }
}

// ==================== weight bf16 tile pack (h only) =======================
__device__ __forceinline__ void packg(const float* __restrict__ src,
                                      ushort* __restrict__ dh,
                                      int Ktot, int otiles, int cofs, int idx) {
    const int j = idx & 7, lane = (idx >> 3) & 63;
    const int ot = (idx >> 9) % otiles;
    const int ks = idx / (512 * otiles);
    const int m = lane & 15, q = lane >> 4;
    const int o = ot * 16 + m, c = cofs + ks * 32 + q * 8 + j;
    const float v = (c < Ktot) ? src[(size_t)o * Ktot + c] : 0.0f;
    dh[idx] = f2bf(v);
}

// ================= fps1 + weight pack, merged launch =======================
__global__ __launch_bounds__(256)
void fps1_prep_kernel(const float* __restrict__ xyz, float* __restrict__ l1xyz,
                 const float* s1w0, const float* s1b0, float4* Wc1,
                 const float* s1w1, ushort* M1W1h,
                 const float* s1w2, ushort* M1W2h,
                 const float* s3w0, ushort* S3W0h,
                 const float* s3w1, ushort* S3W1h,
                 const float* s3w2, ushort* S3W2h,
                 const float* s2w0, const float* s2b0, float4* Wc0,
                 ushort* W0h,
                 const float* s2w1, ushort* W1h,
                 const float* s2w2, ushort* W2h) {
    __shared__ __align__(16) char smem[4096 * 16 + 64 + 512 * 4];
    if (blockIdx.x < 32) {
        fps_body<4096, 512, 256, true>(xyz, l1xyz, blockIdx.x, threadIdx.x, smem);
        return;
    }
    int i = (blockIdx.x - 32) * 256 + threadIdx.x;
    if (i < 64)     { Wc1[i] = make_float4(s1w0[i*3], s1w0[i*3+1], s1w0[i*3+2], s1b0[i]); return; }  i -= 64;
    if (i < 4096)   { packg(s1w1, M1W1h,  64,  4, 0, i); return; }   i -= 4096;
    if (i < 8192)   { packg(s1w2, M1W2h,  64,  8, 0, i); return; }   i -= 8192;
    if (i < 73728)  { packg(s3w0, S3W0h, 259, 16, 0, i); return; }   i -= 73728;
    if (i < 131072) { packg(s3w1, S3W1h, 256, 32, 0, i); return; }   i -= 131072;
    if (i < 524288) { packg(s3w2, S3W2h, 512, 64, 0, i); return; }   i -= 524288;
    if (i < 16384)  { packg(s2w0, W0h, 131,  8, 3, i); return; }     i -= 16384;
    if (i < 16384)  { packg(s2w1, W1h, 128,  8, 0, i); return; }     i -= 16384;
    if (i < 32768)  { packg(s2w2, W2h, 128, 16, 0, i); return; }     i -= 32768;
    if (i < 128) {
        Wc0[i] = make_float4(s2w0[(size_t)i*131+0], s2w0[(size_t)i*131+1],
                             s2w0[(size_t)i*131+2], s2b0[i]);
    }
}

// ============================ Ball query ===================================
template<int N, int NS, bool CHW, int NT>
__global__ __launch_bounds__(NT)
void bq_kernel(float r2, const float* __restrict__ xyz, const float* __restrict__ cen,
               int* __restrict__ gidx, int S) {
    constexpr int WPB = NT / 64;
    __shared__ __align__(16) float4 sp[N];
    const int t = threadIdx.x, lane = t & 63, w = t >> 6;
    const int cen0 = blockIdx.x * WPB;
    const int b = cen0 / S;                     // WPB divides S -> same batch
    if (CHW) {
        const float* base = xyz + (size_t)b * 3 * N;
        for (int i = t; i < N; i += NT)
            sp[i] = make_float4(base[i], base[N + i], base[2 * N + i], 0.0f);
    } else {
        const float* base = xyz + (size_t)b * N * 3;
        for (int i = t; i < N; i += NT)
            sp[i] = make_float4(base[i*3], base[i*3+1], base[i*3+2], 0.0f);
    }
    __syncthreads();
    const int wid = cen0 + w;
    const float cx = cen[(size_t)wid*3+0], cy = cen[(size_t)wid*3+1], cz = cen[(size_t)wid*3+2];
    int* out = gidx + (size_t)wid * NS;
    int cnt = 0, first = -1;
    for (int b0 = 0; b0 < N; b0 += 64) {
        const float4 p = sp[b0 + lane];
        const float dx = p.x - cx, dy = p.y - cy, dz = p.z - cz;
        const float d = __fadd_rn(__fadd_rn(__fmul_rn(dx, dx), __fmul_rn(dy, dy)), __fmul_rn(dz, dz));
        const bool in = (d <= r2);
        const unsigned long long m = __ballot(in);
        if (first < 0 && m != 0ull) first = b0 + __ffsll((unsigned long long)m) - 1;
        const int pos = cnt + (int)__popcll(m & ((1ull << lane) - 1ull));
        if (in && pos < NS) out[pos] = b0 + lane;
        cnt += (int)__popcll(m);
        if (cnt >= NS) break;
    }
    if (cnt < NS)
        for (int k = cnt + lane; k < NS; k += 64) out[k] = first;
}

// ==================== MLP stage 1 (MFMA bf16) + fps2 merged ================
__global__ __launch_bounds__(256)
void mlp1_kernel(const float* __restrict__ xyz, const float* __restrict__ l1xyz,
                 float* __restrict__ l2xyz,
                 const int* __restrict__ gidx, const float4* __restrict__ Wc1,
                 const ushort* __restrict__ W1h, const float* __restrict__ b1,
                 const ushort* __restrict__ W2h, const float* __restrict__ b2,
                 float* __restrict__ l1p) {
    __shared__ __align__(16) char smem[64 * 68 * 4 * 2];   // 34816 B
    float* bufA = (float*)smem;
    float* bufB = (float*)(smem + 64 * 68 * 4);
    const int t = threadIdx.x, b = blockIdx.y;
    if (blockIdx.x == 256) {   // fps2
        fps_body<512, 128, 256, false>(l1xyz, l2xyz, b, t, smem);
        return;
    }
    const int s0 = blockIdx.x * 2;
    {
        const int n = t >> 2, c = t & 3;
        const int s = s0 + (n >> 5);
        const int gi = gidx[((size_t)b * 512 + s) * 32 + (n & 31)];
        float v = 0.0f;
        if (c < 3) v = xyz[(size_t)b * 3 * 4096 + c * 4096 + gi] - l1xyz[((size_t)b * 512 + s) * 3 + c];
        bufB[n * 4 + c] = v;
    }
    __syncthreads();
    {   // layer0: 3 -> 64, exact fp32
        const int o = t & 63, ng = t >> 6;
        const float4 wc = Wc1[o];
        #pragma unroll
        for (int r = 0; r < 16; ++r) {
            const int n = ng * 16 + r;
            const float z = wc.w + wc.x * bufB[n*4] + wc.y * bufB[n*4+1] + wc.z * bufB[n*4+2];
            bufA[n * 68 + o] = fmaxf(z, 0.0f);
        }
    }
    const int lane = t & 63, wv = t >> 6;
    const int m = lane & 15, q = lane >> 4;
    const int rowA = wv * 16 + m;
    // layer1: 64 -> 64
    f32x4 acc1[4];
    #pragma unroll
    for (int ot = 0; ot < 4; ++ot)
        #pragma unroll
        for (int r = 0; r < 4; ++r) acc1[ot][r] = 0.0f;
    #pragma unroll
    for (int ks = 0; ks < 2; ++ks) {
        float xv[8];
        *(float4*)&xv[0] = *(const float4*)&bufA[rowA * 68 + ks * 32 + q * 8];
        *(float4*)&xv[4] = *(const float4*)&bufA[rowA * 68 + ks * 32 + q * 8 + 4];
        SV8 ah;
        #pragma unroll
        for (int j = 0; j < 8; ++j) ah.u[j] = f2bf(xv[j]);
        #pragma unroll
        for (int ot = 0; ot < 4; ++ot) {
            SV8 bh;
            bh.v = *(const short8*)(W1h + (size_t)((ks * 4 + ot) * 64 + lane) * 8);
            acc1[ot] = __builtin_amdgcn_mfma_f32_16x16x32_bf16(ah.v, bh.v, acc1[ot], 0, 0, 0);
        }
    }
    #pragma unroll
    for (int ot = 0; ot < 4; ++ot) {
        const float bb = b1[ot * 16 + m];
        #pragma unroll
        for (int r = 0; r < 4; ++r)
            bufB[(wv * 16 + q * 4 + r) * 68 + ot * 16 + m] = fmaxf(acc1[ot][r] + bb, 0.0f);
    }
    // layer2: 64 -> 128 + per-wave max
    f32x4 acc2[8];
    #pragma unroll
    for (int ot = 0; ot < 8; ++ot)
        #pragma unroll
        for (int r = 0; r < 4; ++r) acc2[ot][r] = 0.0f;
    #pragma unroll
    for (int ks = 0; ks < 2; ++ks) {
        float xv[8];
        *(float4*)&xv[0] = *(const float4*)&bufB[rowA * 68 + ks * 32 + q * 8];
        *(float4*)&xv[4] = *(const float4*)&bufB[rowA * 68 + ks * 32 + q * 8 + 4];
        SV8 ah;
        #pragma unroll
        for (int j = 0; j < 8; ++j) ah.u[j] = f2bf(xv[j]);
        #pragma unroll
        for (int ot = 0; ot < 8; ++ot) {
            SV8 bh;
            bh.v = *(const short8*)(W2h + (size_t)((ks * 8 + ot) * 64 + lane) * 8);
            acc2[ot] = __builtin_amdgcn_mfma_f32_16x16x32_bf16(ah.v, bh.v, acc2[ot], 0, 0, 0);
        }
    }
    __syncthreads();
    #pragma unroll
    for (int ot = 0; ot < 8; ++ot) {
        const float bb = b2[ot * 16 + m];
        float mx = 0.0f;
        #pragma unroll
        for (int r = 0; r < 4; ++r) mx = fmaxf(mx, acc2[ot][r] + bb);
        bufA[(wv * 4 + q) * 128 + ot * 16 + m] = mx;
    }
    __syncthreads();
    {
        const int half = t >> 7, o = t & 127;
        float v = bufA[(half * 8) * 128 + o];
        #pragma unroll
        for (int rr = 1; rr < 8; ++rr) v = fmaxf(v, bufA[(half * 8 + rr) * 128 + o]);
        l1p[((size_t)b * 512 + s0 + half) * 128 + o] = v;
    }
}

// ============================ MLP stage 2 (MFMA bf16) ======================
__global__ __launch_bounds__(256)
void mlp2_kernel(const float* __restrict__ l1xyz, const float* __restrict__ l1p,
                 const float* __restrict__ l2xyz, const int* __restrict__ gidx,
                 const ushort* __restrict__ W0h, const float4* __restrict__ Wc0,
                 const ushort* __restrict__ W1h, const float* __restrict__ b1,
                 const ushort* __restrict__ W2h, const float* __restrict__ b2,
                 float* __restrict__ X3) {
    __shared__ __align__(16) float Abuf[64 * 132];   // x / h2
    __shared__ __align__(16) float Bbuf[64 * 132];   // h1 / max-partials
    __shared__ int sg[64];
    const int t = threadIdx.x, bs = blockIdx.x, b = bs >> 7;
    if (t < 64) sg[t] = gidx[(size_t)bs * 64 + t];
    if (t < 3)  X3[(size_t)bs * 288 + t] = l2xyz[(size_t)bs * 3 + t];     // raw coords
    if (t >= 64 && t < 93) X3[(size_t)bs * 288 + 259 + (t - 64)] = 0.0f;  // zero pad
    __syncthreads();
    for (int i = t; i < 64 * 32; i += 256) {
        const int n = i >> 5, cc = i & 31;
        *(float4*)&Abuf[n * 132 + cc * 4] =
            *(const float4*)&l1p[((size_t)b * 512 + sg[n]) * 128 + cc * 4];
    }
    if (t < 192) {
        const int n = t / 3, c = t % 3;
        Abuf[n * 132 + 128 + c] =
            l1xyz[((size_t)b * 512 + sg[n]) * 3 + c] - l2xyz[(size_t)bs * 3 + c];
    }
    __syncthreads();
    const int lane = t & 63, wv = t >> 6;
    const int m = lane & 15, q = lane >> 4;
    const int rowA = wv * 16 + m;

    // layer 0: feats (K=128) MFMA + coords/bias epilogue
    f32x4 acc0[8];
    #pragma unroll
    for (int ot = 0; ot < 8; ++ot)
        #pragma unroll
        for (int r = 0; r < 4; ++r) acc0[ot][r] = 0.0f;
    #pragma unroll
    for (int ks = 0; ks < 4; ++ks) {
        float xv[8];
        *(float4*)&xv[0] = *(const float4*)&Abuf[rowA * 132 + ks * 32 + q * 8];
        *(float4*)&xv[4] = *(const float4*)&Abuf[rowA * 132 + ks * 32 + q * 8 + 4];
        SV8 ah;
        #pragma unroll
        for (int j = 0; j < 8; ++j) ah.u[j] = f2bf(xv[j]);
        #pragma unroll
        for (int ot = 0; ot < 8; ++ot) {
            SV8 bh;
            bh.v = *(const short8*)(W0h + (size_t)((ks * 8 + ot) * 64 + lane) * 8);
            acc0[ot] = __builtin_amdgcn_mfma_f32_16x16x32_bf16(ah.v, bh.v, acc0[ot], 0, 0, 0);
        }
    }
    float crd[4][3];
    #pragma unroll
    for (int r = 0; r < 4; ++r) {
        const int n = wv * 16 + q * 4 + r;
        crd[r][0] = Abuf[n * 132 + 128];
        crd[r][1] = Abuf[n * 132 + 129];
        crd[r][2] = Abuf[n * 132 + 130];
    }
    #pragma unroll
    for (int ot = 0; ot < 8; ++ot) {
        const float4 wc = Wc0[ot * 16 + m];
        #pragma unroll
        for (int r = 0; r < 4; ++r) {
            const float v = acc0[ot][r] + wc.w + wc.x * crd[r][0] + wc.y * crd[r][1] + wc.z * crd[r][2];
            Bbuf[(wv * 16 + q * 4 + r) * 132 + ot * 16 + m] = fmaxf(v, 0.0f);
        }
    }
    __syncthreads();

    // layer 1: 128 -> 128
    f32x4 acc1[8];
    #pragma unroll
    for (int ot = 0; ot < 8; ++ot)
        #pragma unroll
        for (int r = 0; r < 4; ++r) acc1[ot][r] = 0.0f;
    #pragma unroll
    for (int ks = 0; ks < 4; ++ks) {
        float xv[8];
        *(float4*)&xv[0] = *(const float4*)&Bbuf[rowA * 132 + ks * 32 + q * 8];
        *(float4*)&xv[4] = *(const float4*)&Bbuf[rowA * 132 + ks * 32 + q * 8 + 4];
        SV8 ah;
        #pragma unroll
        for (int j = 0; j < 8; ++j) ah.u[j] = f2bf(xv[j]);
        #pragma unroll
        for (int ot = 0; ot < 8; ++ot) {
            SV8 bh;
            bh.v = *(const short8*)(W1h + (size_t)((ks * 8 + ot) * 64 + lane) * 8);
            acc1[ot] = __builtin_amdgcn_mfma_f32_16x16x32_bf16(ah.v, bh.v, acc1[ot], 0, 0, 0);
        }
    }
    __syncthreads();
    #pragma unroll
    for (int ot = 0; ot < 8; ++ot) {
        const float bb = b1[ot * 16 + m];
        #pragma unroll
        for (int r = 0; r < 4; ++r)
            Abuf[(wv * 16 + q * 4 + r) * 132 + ot * 16 + m] = fmaxf(acc1[ot][r] + bb, 0.0f);
    }
    __syncthreads();

    // layer 2: 128 -> 256, relu+max
    f32x4 acc2[16];
    #pragma unroll
    for (int ot = 0; ot < 16; ++ot)
        #pragma unroll
        for (int r = 0; r < 4; ++r) acc2[ot][r] = 0.0f;
    #pragma unroll
    for (int ks = 0; ks < 4; ++ks) {
        float xv[8];
        *(float4*)&xv[0] = *(const float4*)&Abuf[rowA * 132 + ks * 32 + q * 8];
        *(float4*)&xv[4] = *(const float4*)&Abuf[rowA * 132 + ks * 32 + q * 8 + 4];
        SV8 ah;
        #pragma unroll
        for (int j = 0; j < 8; ++j) ah.u[j] = f2bf(xv[j]);
        #pragma unroll
        for (int ot = 0; ot < 16; ++ot) {
            SV8 bh;
            bh.v = *(const short8*)(W2h + (size_t)((ks * 16 + ot) * 64 + lane) * 8);
            acc2[ot] = __builtin_amdgcn_mfma_f32_16x16x32_bf16(ah.v, bh.v, acc2[ot], 0, 0, 0);
        }
    }
    __syncthreads();
    #pragma unroll
    for (int ot = 0; ot < 16; ++ot) {
        const float bb = b2[ot * 16 + m];
        float mx = 0.0f;
        #pragma unroll
        for (int r = 0; r < 4; ++r) mx = fmaxf(mx, acc2[ot][r] + bb);
        Bbuf[(wv * 4 + q) * 256 + ot * 16 + m] = mx;
    }
    __syncthreads();
    {
        float v = Bbuf[t];
        #pragma unroll
        for (int rr = 1; rr < 16; ++rr) v = fmaxf(v, Bbuf[rr * 256 + t]);
        X3[(size_t)bs * 288 + 3 + t] = v;
    }
}

// ===================== stage-3 GEMM via MFMA bf16 (no LDS A) ===============
template<int KSTEPS, int OTILES, bool MAXOUT>
__global__ __launch_bounds__(256)
void gemm_mfma_kernel(const float* __restrict__ A, int AS,
                      const ushort* __restrict__ Wh,
                      const float* __restrict__ bias, float* __restrict__ C, int O) {
    __shared__ float part[16][OTILES * 16];
    const int t = threadIdx.x, lane = t & 63, wv = t >> 6;
    const int m = lane & 15, q = lane >> 4;
    const int rowA = blockIdx.x * 64 + wv * 16 + m;
    const int bo = blockIdx.y, OT = O >> 4;
    f32x4 acc[OTILES];
    #pragma unroll
    for (int ot = 0; ot < OTILES; ++ot)
        #pragma unroll
        for (int r = 0; r < 4; ++r) acc[ot][r] = 0.0f;
    for (int ks = 0; ks < KSTEPS; ++ks) {
        float xv[8];
        *(float4*)&xv[0] = *(const float4*)&A[(size_t)rowA * AS + ks * 32 + q * 8];
        *(float4*)&xv[4] = *(const float4*)&A[(size_t)rowA * AS + ks * 32 + q * 8 + 4];
        SV8 ah;
        #pragma unroll
        for (int j = 0; j < 8; ++j) ah.u[j] = f2bf(xv[j]);
        #pragma unroll
        for (int ot = 0; ot < OTILES; ++ot) {
            const size_t wb = (size_t)((ks * OT + bo * OTILES + ot) * 64 + lane) * 8;
            SV8 bh;
            bh.v = *(const short8*)(Wh + wb);
            acc[ot] = __builtin_amdgcn_mfma_f32_16x16x32_bf16(ah.v, bh.v, acc[ot], 0, 0, 0);
        }
    }
    if (!MAXOUT) {
        #pragma unroll
        for (int ot = 0; ot < OTILES; ++ot) {
            const int col = (bo * OTILES + ot) * 16 + m;
            const float bb = bias[col];
            #pragma unroll
            for (int r = 0; r < 4; ++r) {
                const int row = blockIdx.x * 64 + wv * 16 + q * 4 + r;
                C[(size_t)row * O + col] = fmaxf(acc[ot][r] + bb, 0.0f);
            }
        }
    } else {
        #pragma unroll
        for (int ot = 0; ot < OTILES; ++ot) {
            const int col = (bo * OTILES + ot) * 16 + m;
            const float bb = bias[col];
            float mx = 0.0f;
            #pragma unroll
            for (int r = 0; r < 4; ++r) mx = fmaxf(mx, acc[ot][r] + bb);
            part[wv * 4 + q][ot * 16 + m] = mx;
        }
        __syncthreads();
        for (int o = t; o < OTILES * 16; o += 256) {
            float v = part[0][o];
            #pragma unroll
            for (int rr = 1; rr < 16; ++rr) v = fmaxf(v, part[rr][o]);
            C[(size_t)blockIdx.x * O + bo * OTILES * 16 + o] = v;
        }
    }
}

// ================= fused FC head (P3 row-max + 3 layers, fp32) =============
__global__ __launch_bounds__(256)
void fchead_kernel(const float* __restrict__ P3,
                   const float* __restrict__ f1w, const float* __restrict__ f1b,
                   const float* __restrict__ f2w, const float* __restrict__ f2b,
                   const float* __restrict__ f3w, const float* __restrict__ f3b,
                   float* __restrict__ out) {
    __shared__ __align__(16) float x[1024];
    __shared__ __align__(16) float h1[512];
    __shared__ __align__(16) float h2[256];
    const int t = threadIdx.x, b = blockIdx.x;
    for (int i = t; i < 1024; i += 256)
        x[i] = fmaxf(P3[(size_t)(2*b)*1024 + i], P3[(size_t)(2*b+1)*1024 + i]);
    __syncthreads();
    #pragma unroll
    for (int oo = 0; oo < 2; ++oo) {       // f1: 1024 -> 512
        const int o = t + oo * 256;
        const float4* wr = (const float4*)(f1w + (size_t)o * 1024);
        float s0 = 0, s1 = 0, s2 = 0, s3 = 0;
        for (int c = 0; c < 256; ++c) {
            const float4 w4 = wr[c];
            const float4 xv = *(const float4*)&x[c * 4];
            s0 += w4.x * xv.x; s1 += w4.y * xv.y; s2 += w4.z * xv.z; s3 += w4.w * xv.w;
        }
        h1[o] = fmaxf(f1b[o] + ((s0 + s1) + (s2 + s3)), 0.0f);
    }
    __syncthreads();
    {                                       // f2: 512 -> 256
        const float4* wr = (const float4*)(f2w + (size_t)t * 512);
        float s0 = 0, s1 = 0, s2 = 0, s3 = 0;
        for (int c = 0; c < 128; ++c) {
            const float4 w4 = wr[c];
            const float4 xv = *(const float4*)&h1[c * 4];
            s0 += w4.x * xv.x; s1 += w4.y * xv.y; s2 += w4.z * xv.z; s3 += w4.w * xv.w;
        }
        h2[t] = fmaxf(f2b[t] + ((s0 + s1) + (s2 + s3)), 0.0f);
    }
    __syncthreads();
    if (t < 6) {                            // f3: 256 -> 6
        const float4* wr = (const float4*)(f3w + (size_t)t * 256);
        float s0 = 0, s1 = 0, s2 = 0, s3 = 0;
        for (int c = 0; c < 64; ++c) {
            const float4 w4 = wr[c];
            const float4 xv = *(const float4*)&h2[c * 4];
            s0 += w4.x * xv.x; s1 += w4.y * xv.y; s2 += w4.z * xv.z; s3 += w4.w * xv.w;
        }
        out[b * 6 + t] = f3b[t] + ((s0 + s1) + (s2 + s3));
    }
}

// ============================ launch =======================================
extern "C" void kernel_launch(void* const* d_in, const int* in_sizes, int n_in,
                              void* d_out, int out_size, void* d_ws, size_t ws_size,
                              hipStream_t stream) {
    const float* xyz  = (const float*)d_in[0];
    const float* s1w0 = (const float*)d_in[1];  const float* s1b0 = (const float*)d_in[2];
    const float* s1w1 = (const float*)d_in[3];  const float* s1b1 = (const float*)d_in[4];
    const float* s1w2 = (const float*)d_in[5];  const float* s1b2 = (const float*)d_in[6];
    const float* s2w0 = (const float*)d_in[7];  const float* s2b0 = (const float*)d_in[8];
    const float* s2w1 = (const float*)d_in[9];  const float* s2b1 = (const float*)d_in[10];
    const float* s2w2 = (const float*)d_in[11]; const float* s2b2 = (const float*)d_in[12];
    const float* s3w0 = (const float*)d_in[13]; const float* s3b0 = (const float*)d_in[14];
    const float* s3w1 = (const float*)d_in[15]; const float* s3b1 = (const float*)d_in[16];
    const float* s3w2 = (const float*)d_in[17]; const float* s3b2 = (const float*)d_in[18];
    const float* f1w  = (const float*)d_in[19]; const float* f1b  = (const float*)d_in[20];
    const float* f2w  = (const float*)d_in[21]; const float* f2b  = (const float*)d_in[22];
    const float* f3w  = (const float*)d_in[23]; const float* f3b  = (const float*)d_in[24];

    char* ws = (char*)d_ws;
    float* l1_xyz = (float*)(ws + 0);              // 32*512*3
    int*   gidx1  = (int*)  (ws + 196608);         // 32*512*32
    float* l1p    = (float*)(ws + 2293760);        // 32*512*128
    float* l2_xyz = (float*)(ws + 10682368);       // 32*128*3
    int*   gidx2  = (int*)  (ws + 10731520);       // 32*128*64
    float* X3p    = (float*)(ws + 11780096);       // 4096*288 (zero-padded)
    const size_t PK = 16498688;                    // pack region (h-only)
    float4* Wc1   = (float4*)(ws + PK + 0);
    ushort* M1W1h = (ushort*)(ws + PK + 1024);
    ushort* M1W2h = (ushort*)(ws + PK + 17408);
    ushort* W0h   = (ushort*)(ws + PK + 50176);
    ushort* W1h   = (ushort*)(ws + PK + 115712);
    ushort* W2h   = (ushort*)(ws + PK + 181248);
    float4* Wc0   = (float4*)(ws + PK + 312320);
    ushort* S3W0h = (ushort*)(ws + PK + 314368);
    ushort* S3W1h = (ushort*)(ws + PK + 609280);
    ushort* S3W2h = (ushort*)(ws + PK + 1133568);
    float* Y1   = (float*)(ws + 19729408);         // 4096*256
    float* Y2   = (float*)(ws + 23923712);         // 4096*512
    float* P3   = (float*)(ws + 32312320);         // 64*1024 fp32 partial maxima

    // Stage 1 (fps1 on blocks 0..31, weight pack on blocks 32..)
    fps1_prep_kernel<<<3186, 256, 0, stream>>>(xyz, l1_xyz,
        s1w0, s1b0, Wc1, s1w1, M1W1h, s1w2, M1W2h,
        s3w0, S3W0h, s3w1, S3W1h, s3w2, S3W2h,
        s2w0, s2b0, Wc0, W0h, s2w1, W1h, s2w2, W2h);
    bq_kernel<4096, 32, true, 1024><<<1024, 1024, 0, stream>>>(
        (float)(0.2 * 0.2), xyz, l1_xyz, gidx1, 512);
    {
        dim3 g(257, 32);   // x==256 -> fps2 for batch y
        mlp1_kernel<<<g, 256, 0, stream>>>(xyz, l1_xyz, l2_xyz, gidx1,
            Wc1, M1W1h, s1b1, M1W2h, s1b2, l1p);
    }

    // Stage 2
    bq_kernel<512, 64, false, 1024><<<256, 1024, 0, stream>>>(
        (float)(0.4 * 0.4), l1_xyz, l2_xyz, gidx2, 128);
    mlp2_kernel<<<4096, 256, 0, stream>>>(l1_xyz, l1p, l2_xyz, gidx2,
        W0h, Wc0, W1h, s2b1, W2h, s2b2, X3p);

    // Stage 3 (bf16 MFMA GEMMs; OTILES=4 everywhere = R13 schedule)
    {
        dim3 g1(64, 4);
        gemm_mfma_kernel<9,  4, false><<<g1, 256, 0, stream>>>(X3p, 288, S3W0h, s3b0, Y1, 256);
        dim3 g2(64, 8);
        gemm_mfma_kernel<8,  4, false><<<g2, 256, 0, stream>>>(Y1, 256, S3W1h, s3b1, Y2, 512);
        dim3 g3(64, 16);
        gemm_mfma_kernel<16, 4, true ><<<g3, 256, 0, stream>>>(Y2, 512, S3W2h, s3b2, P3, 1024);
    }

    // Fused FC head (row-max of P3 + 1024->512->256->6)
    fchead_kernel<<<32, 256, 0, stream>>>(P3, f1w, f1b, f2w, f2b, f3w, f3b, (float*)d_out);
    (void)in_sizes; (void)n_in; (void)out_size; (void)ws_size;
}